// Round 14
// baseline (292.938 us; speedup 1.0000x reference)
//
#include <hip/hip_runtime.h>
#include <cstdint>
#include <cstddef>

#define DEV __device__ __forceinline__

typedef __attribute__((ext_vector_type(4))) float f32x4;
typedef __attribute__((ext_vector_type(2))) float f32x2;
typedef __attribute__((ext_vector_type(4))) unsigned int u32x4;
typedef __attribute__((ext_vector_type(2))) unsigned int u32x2;
typedef unsigned short ushort_t;

constexpr int NN  = 8192;   // decoder nodes
constexpr int MMM = 8192;   // encoder memory nodes
constexpr int DD  = 512;    // d_model
constexpr int DFF = 2048;   // ff hidden

// ---------- helpers ----------
DEV unsigned short f2bf(float f) {
  unsigned int u = __builtin_bit_cast(unsigned int, f);
  u += 0x7fffu + ((u >> 16) & 1u);           // round-to-nearest-even
  return (unsigned short)(u >> 16);
}
DEV float bflo(unsigned int u) { return __builtin_bit_cast(float, u << 16); }
DEV float bfhi(unsigned int u) { return __builtin_bit_cast(float, u & 0xffff0000u); }
DEV unsigned char f2fp8(float f) {            // f32 -> OCP e4m3fn via HW (RNE, saturating)
  int p = __builtin_amdgcn_cvt_pk_fp8_f32(f, f, 0, false);
  return (unsigned char)(p & 0xff);
}

// kv2 layout: [pass h:2][node:8192][512B], row = 32 x 16B units: [k 8B | v 8B].
DEV void store_kv(unsigned char* kv2, long node, int cc /*0..1023: k|v*/, float val) {
  int h, off;
  if (cc < 512) { h = cc >> 8; const int r = cc & 255; off = ((r >> 3) << 4) + (r & 7); }
  else { const int cv = cc - 512; h = cv >> 8; const int r = cv & 255; off = ((r >> 3) << 4) + 8 + (r & 7); }
  kv2[((long)h * 8192 + node) * 512 + off] = f2fp8(val);
}

DEV void gload_lds16(const void* g, void* l) {
  __builtin_amdgcn_global_load_lds((__attribute__((address_space(1))) void*)g,
                                   (__attribute__((address_space(3))) void*)l,
                                   16, 0, 0);
}

// XCD-locality block swizzle: wgid%8 selects XCD (round-robin dispatch).
DEV void xcd_rc(int l, int gx, int gy, int& row, int& col) {
  const int xcd = l & 7;
  const int idx = l >> 3;
  const int rpx = gx >> 3;          // row-panels per XCD
  row = xcd * rpx + idx / gy;
  col = idx % gy;
}

// ---------- weight transpose + bf16 convert: in [R][C] f32 -> out [C][R] bf16 ----------
__global__ void transw_kernel(const float* __restrict__ in, ushort_t* __restrict__ out,
                              int R, int C) {
  __shared__ float t[32][33];
  const int x0 = blockIdx.x * 32, y0 = blockIdx.y * 32;
  const int tx = threadIdx.x, ty = threadIdx.y;   // block (32,8)
#pragma unroll
  for (int i = 0; i < 4; ++i)
    t[ty + i * 8][tx] = in[(long)(y0 + ty + i * 8) * C + x0 + tx];
  __syncthreads();
#pragma unroll
  for (int i = 0; i < 4; ++i)
    out[(long)(x0 + ty + i * 8) * R + y0 + tx] = f2bf(t[tx][ty + i * 8]);
}

struct TW4 {
  const float* in0; const float* in1; const float* in2; const float* in3;
  ushort_t* o0; ushort_t* o1; ushort_t* o2; ushort_t* o3;
};
__global__ void transw4_kernel(TW4 p) {
  const float* in; ushort_t* out;
  switch (blockIdx.z) {
    case 0:  in = p.in0; out = p.o0; break;
    case 1:  in = p.in1; out = p.o1; break;
    case 2:  in = p.in2; out = p.o2; break;
    default: in = p.in3; out = p.o3; break;
  }
  __shared__ float t[32][33];
  const int x0 = blockIdx.x * 32, y0 = blockIdx.y * 32;
  const int tx = threadIdx.x, ty = threadIdx.y;   // block (32,8)
#pragma unroll
  for (int i = 0; i < 4; ++i)
    t[ty + i * 8][tx] = in[(long)(y0 + ty + i * 8) * 512 + x0 + tx];
  __syncthreads();
#pragma unroll
  for (int i = 0; i < 4; ++i)
    out[(long)(x0 + ty + i * 8) * 512 + y0 + tx] = f2bf(t[tx][ty + i * 8]);
}

// ---------- f32 -> bf16 elementwise (4/thread) ----------
__global__ void tobf_kernel(const float* __restrict__ in, ushort_t* __restrict__ out, int n4) {
  int i = blockIdx.x * blockDim.x + threadIdx.x;
  if (i >= n4) return;
  f32x4 v = ((const f32x4*)in)[i];
  u32x2 o;
  o[0] = (unsigned)f2bf(v[0]) | ((unsigned)f2bf(v[1]) << 16);
  o[1] = (unsigned)f2bf(v[2]) | ((unsigned)f2bf(v[3]) << 16);
  ((u32x2*)out)[i] = o;
}

// ---------- concat q/k/v biases into one [1536] vector ----------
__global__ void biascat_kernel(const float* __restrict__ bq, const float* __restrict__ bk,
                               const float* __restrict__ bv, float* __restrict__ o) {
  const int i = blockIdx.x * blockDim.x + threadIdx.x;
  if (i >= 1536) return;
  o[i] = (i < 512) ? bq[i] : ((i < 1024) ? bk[i - 512] : bv[i - 1024]);
}

// ---------- LayerNorm: f32 in -> bf16 out, one wave per row of 512 ----------
__global__ __launch_bounds__(256)
void ln_kernel(const float* __restrict__ x, const float* __restrict__ g,
               const float* __restrict__ b, ushort_t* __restrict__ out) {
  const int row  = blockIdx.x * 4 + (threadIdx.x >> 6);
  const int lane = threadIdx.x & 63;
  const float* xr = x + (long)row * DD + lane * 8;
  float v[8];
  *(f32x4*)&v[0] = *(const f32x4*)&xr[0];
  *(f32x4*)&v[4] = *(const f32x4*)&xr[4];
  float s = 0.f, sq = 0.f;
#pragma unroll
  for (int i = 0; i < 8; ++i) { s += v[i]; sq += v[i] * v[i]; }
#pragma unroll
  for (int o = 1; o < 64; o <<= 1) { s += __shfl_xor(s, o); sq += __shfl_xor(sq, o); }
  const float mu   = s * (1.f / 512.f);
  const float var  = sq * (1.f / 512.f) - mu * mu;
  const float rstd = rsqrtf(var + 1e-6f);
  const float* gp = g + lane * 8;
  const float* bp = b + lane * 8;
  u32x4 o8;
#pragma unroll
  for (int u = 0; u < 4; ++u) {
    unsigned int lo = f2bf((v[2 * u]     - mu) * rstd * gp[2 * u]     + bp[2 * u]);
    unsigned int hi = f2bf((v[2 * u + 1] - mu) * rstd * gp[2 * u + 1] + bp[2 * u + 1]);
    o8[u] = lo | (hi << 16);
  }
  *(u32x4*)(out + (long)row * DD + lane * 8) = o8;
}

// ==================== GEMM kernels (T2 XOR-swizzled LDS, single-buffer, T1 XCD swizzle) ====

// ---------- bf16 MFMA GEMM 128x128 tile (1D grid, XCD-banded) ----------
// EPI 0: bf16 (bias); 1: bf16 (bias+relu); 2: f32 (bias+residual);
// EPI 3: fp8 kv2 out (bias); EPI 4: split qkv -> q bf16 (c<512), k|v fp8 kv2 (c>=512)
template <int EPI>
__global__ __launch_bounds__(256, 4)
void gemm_kernel(const ushort_t* __restrict__ A, const ushort_t* __restrict__ Bt,
                 const float* __restrict__ bias, const float* res,
                 float* outF, ushort_t* outB, unsigned char* out8, int M, int N, int K) {
  __shared__ __align__(16) ushort_t sA[128 * 64];
  __shared__ __align__(16) ushort_t sB[128 * 64];
  const int tid  = threadIdx.x;
  const int lane = tid & 63;
  const int w    = tid >> 6;
  const int wr   = w >> 1, wc = w & 1;
  int brc, bcc;
  xcd_rc(blockIdx.x, M >> 7, N >> 7, brc, bcc);
  const long brow = (long)brc * 128;
  const long bcol = (long)bcc * 128;
  const int r16 = lane & 15;
  const int cq  = lane >> 4;                  // 16B-chunk quarter 0..3
  f32x4 acc[4][4] = {};

  for (int k0 = 0; k0 < K; k0 += 64) {
    __syncthreads();
#pragma unroll
    for (int i = 0; i < 4; ++i) {
      const int c   = i * 256 + tid;
      const int wb  = i * 256 + (tid & ~63);  // wave-uniform chunk base (linear LDS dest)
      const int row = c >> 3;
      const int col = ((c & 7) ^ (row & 7)) << 3;   // pre-swizzled source column
      gload_lds16(A  + (brow + row) * (long)K + k0 + col, &sA[(long)wb * 8]);
      gload_lds16(Bt + (bcol + row) * (long)K + k0 + col, &sB[(long)wb * 8]);
    }
    __syncthreads();
#pragma unroll
    for (int kkc = 0; kkc < 8; kkc += 4) {    // kkc: 0 -> k 0..31, 4 -> k 32..63
      u32x4 af[4], bfr[4];
#pragma unroll
      for (int i = 0; i < 4; ++i) {
        const int row = wr * 64 + i * 16 + r16;
        af[i] = *(const u32x4*)&sA[row * 64 + (((kkc + cq) ^ (row & 7)) << 3)];
      }
#pragma unroll
      for (int j = 0; j < 4; ++j) {
        const int row = wc * 64 + j * 16 + r16;
        bfr[j] = *(const u32x4*)&sB[row * 64 + (((kkc + cq) ^ (row & 7)) << 3)];
      }
#pragma unroll
      for (int i = 0; i < 4; ++i)
#pragma unroll
        for (int j = 0; j < 4; ++j)
          asm("v_mfma_f32_16x16x32_bf16 %0, %1, %2, %0"
              : "+v"(acc[i][j]) : "v"(af[i]), "v"(bfr[j]));
    }
  }
  asm volatile("s_nop 7\n\ts_nop 7\n\ts_nop 7" ::);  // MFMA->VALU hazard guard

  const long orow = brow + wr * 64;
  const long ocol = bcol + wc * 64;
#pragma unroll
  for (int j = 0; j < 4; ++j) {
    const long c  = ocol + j * 16 + r16;
    const float bv = bias[c];
#pragma unroll
    for (int i = 0; i < 4; ++i) {
      const long r0 = orow + i * 16 + ((lane >> 4) << 2);
#pragma unroll
      for (int r = 0; r < 4; ++r) {
        float v = acc[i][j][r] + bv;
        const long row = r0 + r;
        if (EPI == 0)      outB[row * (long)N + c] = f2bf(v);
        else if (EPI == 1) outB[row * (long)N + c] = f2bf(fmaxf(v, 0.f));
        else if (EPI == 2) outF[row * (long)N + c] = v + res[row * (long)N + c];
        else if (EPI == 3) store_kv(out8, row, (int)c, v);
        else {  // EPI 4: qkv split
          if (c < 512) outB[row * 512 + c] = f2bf(v);
          else         store_kv(out8, row, (int)c - 512, v);
        }
      }
    }
  }
}

// ---------- bf16 MFMA GEMM 64x64 tile (N <= 1024), 16KB LDS, XCD-banded ----------
template <int EPI>
__global__ __launch_bounds__(256, 8)
void gemm64b_kernel(const ushort_t* __restrict__ A, const ushort_t* __restrict__ Bt,
                    const float* __restrict__ bias, const float* res,
                    float* outF, ushort_t* outB, unsigned char* out8, int M, int N, int K) {
  __shared__ __align__(16) ushort_t sA[64 * 64];
  __shared__ __align__(16) ushort_t sB[64 * 64];
  const int tid  = threadIdx.x;
  const int lane = tid & 63;
  const int w    = tid >> 6;
  const int wr   = w >> 1, wc = w & 1;     // 2x2 waves, each owns 32x32
  int brc, bcc;
  xcd_rc(blockIdx.x, M >> 6, N >> 6, brc, bcc);
  const long brow = (long)brc * 64;
  const long bcol = (long)bcc * 64;
  const int r16 = lane & 15;
  const int cq  = lane >> 4;
  f32x4 acc[2][2] = {};

  for (int k0 = 0; k0 < K; k0 += 64) {
    __syncthreads();
#pragma unroll
    for (int i = 0; i < 2; ++i) {
      const int c   = i * 256 + tid;
      const int wb  = i * 256 + (tid & ~63);
      const int row = c >> 3;
      const int col = ((c & 7) ^ (row & 7)) << 3;
      gload_lds16(A  + (brow + row) * (long)K + k0 + col, &sA[(long)wb * 8]);
      gload_lds16(Bt + (bcol + row) * (long)K + k0 + col, &sB[(long)wb * 8]);
    }
    __syncthreads();
#pragma unroll
    for (int kkc = 0; kkc < 8; kkc += 4) {
      u32x4 af[2], bfr[2];
#pragma unroll
      for (int i = 0; i < 2; ++i) {
        const int row = wr * 32 + i * 16 + r16;
        af[i] = *(const u32x4*)&sA[row * 64 + (((kkc + cq) ^ (row & 7)) << 3)];
      }
#pragma unroll
      for (int j = 0; j < 2; ++j) {
        const int row = wc * 32 + j * 16 + r16;
        bfr[j] = *(const u32x4*)&sB[row * 64 + (((kkc + cq) ^ (row & 7)) << 3)];
      }
#pragma unroll
      for (int i = 0; i < 2; ++i)
#pragma unroll
        for (int j = 0; j < 2; ++j)
          asm("v_mfma_f32_16x16x32_bf16 %0, %1, %2, %0"
              : "+v"(acc[i][j]) : "v"(af[i]), "v"(bfr[j]));
    }
  }
  asm volatile("s_nop 7\n\ts_nop 7\n\ts_nop 7" ::);

  const long orow = brow + wr * 32;
  const long ocol = bcol + wc * 32;
#pragma unroll
  for (int j = 0; j < 2; ++j) {
    const long c  = ocol + j * 16 + r16;
    const float bv = bias[c];
#pragma unroll
    for (int i = 0; i < 2; ++i) {
      const long r0 = orow + i * 16 + ((lane >> 4) << 2);
#pragma unroll
      for (int r = 0; r < 4; ++r) {
        float v = acc[i][j][r] + bv;
        const long row = r0 + r;
        if (EPI == 0)      outB[row * (long)N + c] = f2bf(v);
        else if (EPI == 1) outB[row * (long)N + c] = f2bf(fmaxf(v, 0.f));
        else if (EPI == 2) outF[row * (long)N + c] = v + res[row * (long)N + c];
        else               store_kv(out8, row, (int)c, v);   // EPI 3: kv2
      }
    }
  }
}

// ---------- CSR build: single-pass counting sort by dst ----------
__global__ void zero_kernel(int* p, int n) {
  int i = blockIdx.x * blockDim.x + threadIdx.x;
  if (i < n) p[i] = 0;
}
__global__ void hist2_kernel(const int* __restrict__ d0, const int* __restrict__ d1,
                             int* __restrict__ counts2, int E) {
  const int* d = blockIdx.y ? d1 : d0;
  int* c = counts2 + blockIdx.y * 8192;
  for (int e = blockIdx.x * blockDim.x + threadIdx.x; e < E; e += gridDim.x * blockDim.x)
    atomicAdd(&c[d[e]], 1);
}
template <int PER, int BINS>
__global__ void scan_kernel(const int* __restrict__ countsN, int* __restrict__ rowstartN,
                            int* __restrict__ cursorN) {
  const int* counts = countsN + blockIdx.x * BINS;
  int* rowstart = rowstartN + blockIdx.x * (BINS + 1);
  int* cursor   = cursorN + blockIdx.x * BINS;
  __shared__ int part[256];
  const int t = threadIdx.x;
  int loc[PER];
  int s = 0;
  const int base = t * PER;
#pragma unroll
  for (int i = 0; i < PER; ++i) { loc[i] = counts[base + i]; s += loc[i]; }
  part[t] = s;
  __syncthreads();
  for (int off = 1; off < 256; off <<= 1) {
    int v2 = (t >= off) ? part[t - off] : 0;
    __syncthreads();
    part[t] += v2;
    __syncthreads();
  }
  int run = part[t] - s;   // exclusive prefix
#pragma unroll
  for (int i = 0; i < PER; ++i) { rowstart[base + i] = run; cursor[base + i] = run; run += loc[i]; }
  if (t == 255) rowstart[BINS] = run;
}
__global__ void scatterD_kernel(const int* __restrict__ s0, const int* __restrict__ d0,
                                const int* __restrict__ s1, const int* __restrict__ d1,
                                int* __restrict__ cursorD2,
                                int* __restrict__ o0, int* __restrict__ o1, int E) {
  const int* s = blockIdx.y ? s1 : s0;
  const int* d = blockIdx.y ? d1 : d0;
  int* cur = cursorD2 + blockIdx.y * 8192;
  int* o = blockIdx.y ? o1 : o0;
  for (int e = blockIdx.x * blockDim.x + threadIdx.x; e += 0, e < E; e += gridDim.x * blockDim.x) {
    const int p = atomicAdd(&cur[d[e]], 1);
    o[p] = s[e];
  }
}

// ---------- graph attention, head-split: pass h covers dims [h*256, h*256+256) ----------
// Wave handles TWO dsts (half-wave each: 32 lanes x 16B unit [k 8B | v 8B]).
// Per-pass k/v slice = 4MB -> fits each XCD's L2; one dwordx4 per edge per lane.
#define AT2_LOADI(SD, EB)                                                   \
  _Pragma("unroll") for (int jj = 0; jj < 4; ++jj) {                        \
    int e_ = (EB) + jj;                                                     \
    SD[jj] = srcs[e_ < e1 ? e_ : e1 - 1];                                   \
  }
#define AT2_LOADG(KV, SD)                                                   \
  _Pragma("unroll") for (int jj = 0; jj < 4; ++jj)                          \
    KV[jj] = *(const u32x4*)(kvb + (long)SD[jj] * 512 + boff);
#define AT2_EDGE(KV, VALID)                                                 \
  {                                                                         \
    f32x2 d2_ = {0.f, 0.f};                                                 \
    d2_ += (f32x2)__builtin_amdgcn_cvt_pk_f32_fp8((KV)[0], false) * q2[0];  \
    d2_ += (f32x2)__builtin_amdgcn_cvt_pk_f32_fp8((KV)[0], true)  * q2[1];  \
    d2_ += (f32x2)__builtin_amdgcn_cvt_pk_f32_fp8((KV)[1], false) * q2[2];  \
    d2_ += (f32x2)__builtin_amdgcn_cvt_pk_f32_fp8((KV)[1], true)  * q2[3];  \
    float dot_ = d2_[0] + d2_[1];                                           \
    dot_ += __shfl_xor(dot_, 1);                                            \
    dot_ += __shfl_xor(dot_, 2);                                            \
    dot_ += __shfl_xor(dot_, 4);                                            \
    float sc_ = __expf(fminf(fmaxf(dot_ * 0.125f, -10.f), 10.f));           \
    sc_ = (VALID) ? sc_ : 0.f;                                              \
    z += sc_;                                                               \
    const f32x2 s2_ = {sc_, sc_};                                           \
    av[0] += s2_ * (f32x2)__builtin_amdgcn_cvt_pk_f32_fp8((KV)[2], false);  \
    av[1] += s2_ * (f32x2)__builtin_amdgcn_cvt_pk_f32_fp8((KV)[2], true);   \
    av[2] += s2_ * (f32x2)__builtin_amdgcn_cvt_pk_f32_fp8((KV)[3], false);  \
    av[3] += s2_ * (f32x2)__builtin_amdgcn_cvt_pk_f32_fp8((KV)[3], true);   \
  }
#define AT2_GROUP(GB, KV4)                                                  \
  _Pragma("unroll") for (int jj = 0; jj < 4; ++jj) {                        \
    AT2_EDGE(KV4[jj], ((GB) + jj < n))                                      \
  }

__global__ __launch_bounds__(256)
void attend2_kernel(const int* __restrict__ rowstart, const int* __restrict__ srcs,
                    const ushort_t* __restrict__ qb,
                    const unsigned char* __restrict__ kvb,  // pass base: [8192][512]
                    ushort_t* __restrict__ ob, int hoff) {  // hoff = h*256 (dim offset)
  const int wid  = blockIdx.x * 4 + (threadIdx.x >> 6);
  const int lane = threadIdx.x & 63;
  const int l32  = lane & 31;
  const int d    = 2 * wid + (lane >> 5);      // half-wave owns one dst
  const int boff = l32 * 16;                   // one 16B unit per lane
  const int e0 = rowstart[d], e1 = rowstart[d + 1];
  const int n  = e1 - e0;
  int nmax = n;
  nmax = max(nmax, __shfl_xor(nmax, 32));      // loop bound covers both halves
  const u32x4 qv = *(const u32x4*)(qb + (long)d * DD + hoff + l32 * 8);
  f32x2 q2[4];
#pragma unroll
  for (int u = 0; u < 4; ++u) q2[u] = f32x2{bflo(qv[u]), bfhi(qv[u])};
  f32x2 av[4] = {};
  float z = 0.f;
  if (nmax > 0) {
    int sA4[4], sB4[4];
    u32x4 kvA[4], kvB[4];
    AT2_LOADI(sA4, e0);
    AT2_LOADI(sB4, e0 + 4);
    AT2_LOADG(kvA, sA4);
    const int ng = (nmax + 3) >> 2;
    const int NG = (ng + 1) & ~1;            // even # of groups; tail masked by sc=0
    for (int g = 0; g < NG; g += 2) {
      AT2_LOADG(kvB, sB4);                   // issue group g+1 gathers
      AT2_LOADI(sA4, e0 + (g + 2) * 4);      // indices for group g+2
      AT2_GROUP(g * 4, kvA)                  // compute group g
      AT2_LOADG(kvA, sA4);                   // issue group g+2 gathers
      AT2_LOADI(sB4, e0 + (g + 3) * 4);      // indices for group g+3
      AT2_GROUP((g + 1) * 4, kvB)            // compute group g+1
    }
  }
  const float inv = 1.f / z;
  u32x4 o;
#pragma unroll
  for (int u = 0; u < 4; ++u)
    o[u] = (unsigned)f2bf(av[u][0] * inv) | ((unsigned)f2bf(av[u][1] * inv) << 16);
  *(u32x4*)(ob + (long)d * DD + hoff + l32 * 8) = o;
}

// ---------- host orchestration ----------
extern "C" void kernel_launch(void* const* d_in, const int* in_sizes, int n_in,
                              void* d_out, int out_size, void* d_ws, size_t ws_size,
                              hipStream_t stream) {
  const float* x    = (const float*)d_in[0];
  const float* mem  = (const float*)d_in[1];
  const float* ln0g = (const float*)d_in[2];  const float* ln0b = (const float*)d_in[3];
  const float* ln1g = (const float*)d_in[4];  const float* ln1b = (const float*)d_in[5];
  const float* ln2g = (const float*)d_in[6];  const float* ln2b = (const float*)d_in[7];
  const float* Wq = (const float*)d_in[8];   const float* bq = (const float*)d_in[9];
  const float* Wk = (const float*)d_in[10];  const float* bk = (const float*)d_in[11];
  const float* Wv = (const float*)d_in[12];  const float* bv = (const float*)d_in[13];
  const float* Wo = (const float*)d_in[14];  const float* bo = (const float*)d_in[15];
  const float* W1 = (const float*)d_in[16];  const float* b1 = (const float*)d_in[17];
  const float* W2 = (const float*)d_in[18];  const float* b2 = (const float*)d_in[19];
  const int* src_self  = (const int*)d_in[20];
  const int* dst_self  = (const int*)d_in[21];
  const int* src_cross = (const int*)d_in[22];
  const int* dst_cross = (const int*)d_in[23];
  const int E = in_sizes[20];
  float* out = (float*)d_out;

  char* wsp = (char*)d_ws;
  auto alloc = [&](size_t bytes) {
    char* p = wsp;
    wsp += (bytes + 255) & ~(size_t)255;
    return p;
  };
  ushort_t* Wqkv_t = (ushort_t*)alloc((size_t)1536 * 512 * 2);
  ushort_t* Wo_t   = (ushort_t*)alloc((size_t)512 * 512 * 2);
  ushort_t* W1_t   = (ushort_t*)alloc((size_t)DFF * DD * 2);
  ushort_t* W2_t   = (ushort_t*)alloc((size_t)DD * DFF * 2);
  float*    bqkv   = (float*)alloc(1536 * 4);
  ushort_t* h_bf   = (ushort_t*)alloc((size_t)NN * DD * 2);
  ushort_t* mem_bf = (ushort_t*)alloc((size_t)MMM * DD * 2);
  ushort_t* q_bf   = (ushort_t*)alloc((size_t)NN * DD * 2);         // q (self / cross reuse)
  unsigned char* kv2 = (unsigned char*)alloc((size_t)2 * NN * 512); // fp8 kv, pass-major
  ushort_t* attn_bf= (ushort_t*)alloc((size_t)NN * DD * 2);
  ushort_t* ffh_bf = (ushort_t*)alloc((size_t)NN * DFF * 2);
  int* countsD   = (int*)alloc(2 * 8192 * 4);
  int* rowstartD2= (int*)alloc(2 * 8193 * 4);
  int* cursorD2  = (int*)alloc(2 * 8192 * 4);
  int* srcsA     = (int*)alloc((size_t)E * 4);
  int* srcsB     = (int*)alloc((size_t)E * 4);

  const dim3 B256(256);

  // ---- prep: weights, mem cast, both dst-CSRs (input-only deps) ----
  TW4 tw{Wq, Wk, Wv, Wo, Wqkv_t, Wqkv_t + 512 * 512, Wqkv_t + 1024 * 512, Wo_t};
  transw4_kernel<<<dim3(16, 16, 4), dim3(32, 8), 0, stream>>>(tw);
  transw_kernel<<<dim3(64, 16), dim3(32, 8), 0, stream>>>(W1, W1_t, DD, DFF);
  transw_kernel<<<dim3(16, 64), dim3(32, 8), 0, stream>>>(W2, W2_t, DFF, DD);
  biascat_kernel<<<dim3(6), B256, 0, stream>>>(bq, bk, bv, bqkv);
  tobf_kernel<<<dim3(MMM * DD / 4 / 256), B256, 0, stream>>>(mem, mem_bf, MMM * DD / 4);
  zero_kernel<<<dim3(64), B256, 0, stream>>>(countsD, 2 * 8192);
  hist2_kernel<<<dim3(256, 2), B256, 0, stream>>>(dst_self, dst_cross, countsD, E);
  scan_kernel<32, 8192><<<dim3(2), B256, 0, stream>>>(countsD, rowstartD2, cursorD2);
  scatterD_kernel<<<dim3(256, 2), B256, 0, stream>>>(src_self, dst_self, src_cross, dst_cross,
                                                     cursorD2, srcsA, srcsB, E);

  auto gemm = [&](int mode, const ushort_t* Ap, const ushort_t* Btp, const float* biasp,
                  const float* resp, float* oF, ushort_t* oB, unsigned char* o8,
                  int M_, int N_, int K_) {
    if (N_ <= 1024) {
      dim3 g((M_ / 64) * (N_ / 64));
      if (mode == 0)
        gemm64b_kernel<0><<<g, B256, 0, stream>>>(Ap, Btp, biasp, resp, oF, oB, o8, M_, N_, K_);
      else if (mode == 1)
        gemm64b_kernel<1><<<g, B256, 0, stream>>>(Ap, Btp, biasp, resp, oF, oB, o8, M_, N_, K_);
      else if (mode == 2)
        gemm64b_kernel<2><<<g, B256, 0, stream>>>(Ap, Btp, biasp, resp, oF, oB, o8, M_, N_, K_);
      else
        gemm64b_kernel<3><<<g, B256, 0, stream>>>(Ap, Btp, biasp, resp, oF, oB, o8, M_, N_, K_);
    } else {
      dim3 g((M_ / 128) * (N_ / 128));
      if (mode == 0)
        gemm_kernel<0><<<g, B256, 0, stream>>>(Ap, Btp, biasp, resp, oF, oB, o8, M_, N_, K_);
      else if (mode == 1)
        gemm_kernel<1><<<g, B256, 0, stream>>>(Ap, Btp, biasp, resp, oF, oB, o8, M_, N_, K_);
      else if (mode == 2)
        gemm_kernel<2><<<g, B256, 0, stream>>>(Ap, Btp, biasp, resp, oF, oB, o8, M_, N_, K_);
      else if (mode == 3)
        gemm_kernel<3><<<g, B256, 0, stream>>>(Ap, Btp, biasp, resp, oF, oB, o8, M_, N_, K_);
      else
        gemm_kernel<4><<<g, B256, 0, stream>>>(Ap, Btp, biasp, resp, oF, oB, o8, M_, N_, K_);
    }
  };
  auto attend = [&](const int* rs, const int* sc) {
    attend2_kernel<<<dim3(1024), B256, 0, stream>>>(rs, sc, q_bf, kv2, attn_bf, 0);
    attend2_kernel<<<dim3(1024), B256, 0, stream>>>(rs, sc, q_bf,
                                                    kv2 + (size_t)NN * 512, attn_bf, 256);
  };

  // ---- sublayer 0: self-attention ----
  ln_kernel<<<dim3(NN / 4), B256, 0, stream>>>(x, ln0g, ln0b, h_bf);
  gemm(4, h_bf, Wqkv_t, bqkv, nullptr, nullptr, q_bf, kv2, NN, 1536, DD);   // q bf16 | kv2 fp8
  attend(rowstartD2, srcsA);
  gemm(2, attn_bf, Wo_t, bo, x, out, nullptr, nullptr, NN, DD, DD);    // out = x + attn@Wo+bo

  // ---- sublayer 1: cross-attention ----
  ln_kernel<<<dim3(NN / 4), B256, 0, stream>>>(out, ln1g, ln1b, h_bf);
  gemm(0, h_bf, Wqkv_t, bqkv, nullptr, nullptr, q_bf, nullptr, NN, 512, DD);         // q bf16
  gemm(3, mem_bf, Wqkv_t + 512 * 512, bqkv + 512, nullptr, nullptr, nullptr, kv2,
       MMM, 1024, DD);                                                 // k|v fp8 kv2 (no LN)
  attend(rowstartD2 + 8193, srcsB);
  gemm(2, attn_bf, Wo_t, bo, out, out, nullptr, nullptr, NN, DD, DD);  // out += attn@Wo+bo

  // ---- sublayer 2: feed-forward ----
  ln_kernel<<<dim3(NN / 4), B256, 0, stream>>>(out, ln2g, ln2b, h_bf);
  gemm(1, h_bf, W1_t, b1, nullptr, nullptr, ffh_bf, nullptr, NN, DFF, DD);   // relu, bf16 out
  gemm(2, ffh_bf, W2_t, b2, out, out, nullptr, nullptr, NN, DD, DFF);        // out += ff@W2+b2

  (void)n_in; (void)out_size; (void)ws_size; (void)in_sizes;
}

// Round 15
// 277.051 us; speedup vs baseline: 1.0573x; 1.0573x over previous
//
#include <hip/hip_runtime.h>
#include <cstdint>
#include <cstddef>

#define DEV __device__ __forceinline__

typedef __attribute__((ext_vector_type(4))) float f32x4;
typedef __attribute__((ext_vector_type(2))) float f32x2;
typedef __attribute__((ext_vector_type(4))) unsigned int u32x4;
typedef __attribute__((ext_vector_type(2))) unsigned int u32x2;
typedef unsigned short ushort_t;

constexpr int NN  = 8192;   // decoder nodes
constexpr int MMM = 8192;   // encoder memory nodes
constexpr int DD  = 512;    // d_model
constexpr int DFF = 2048;   // ff hidden

// ---------- helpers ----------
DEV unsigned short f2bf(float f) {
  unsigned int u = __builtin_bit_cast(unsigned int, f);
  u += 0x7fffu + ((u >> 16) & 1u);           // round-to-nearest-even
  return (unsigned short)(u >> 16);
}
DEV float bflo(unsigned int u) { return __builtin_bit_cast(float, u << 16); }
DEV float bfhi(unsigned int u) { return __builtin_bit_cast(float, u & 0xffff0000u); }
DEV unsigned char f2fp8(float f) {            // f32 -> OCP e4m3fn via HW (RNE, saturating)
  int p = __builtin_amdgcn_cvt_pk_fp8_f32(f, f, 0, false);
  return (unsigned char)(p & 0xff);
}

// kvi layout: [node][64 units x 16B], unit i = [k dims 8i..8i+7 (8B) | v dims 8i..8i+7 (8B)].
// One dwordx4 per lane per edge fetches both k and v fragments.
DEV void store_kv(unsigned char* kvi, long node, int cc /*0..1023: k|v*/, float val) {
  int off;
  if (cc < 512) off = ((cc >> 3) << 4) + (cc & 7);
  else { const int cv = cc - 512; off = ((cv >> 3) << 4) + 8 + (cv & 7); }
  kvi[node * 1024 + off] = f2fp8(val);
}

DEV void gload_lds16(const void* g, void* l) {
  __builtin_amdgcn_global_load_lds((__attribute__((address_space(1))) void*)g,
                                   (__attribute__((address_space(3))) void*)l,
                                   16, 0, 0);
}

// XCD-locality block swizzle: wgid%8 selects XCD (round-robin dispatch). Each XCD
// owns a contiguous band of row-panels across ALL columns.
DEV void xcd_rc(int l, int gx, int gy, int& row, int& col) {
  const int xcd = l & 7;
  const int idx = l >> 3;
  const int rpx = gx >> 3;          // row-panels per XCD
  row = xcd * rpx + idx / gy;
  col = idx % gy;
}

// ---------- weight transpose + bf16 convert: in [R][C] f32 -> out [C][R] bf16 ----------
__global__ void transw_kernel(const float* __restrict__ in, ushort_t* __restrict__ out,
                              int R, int C) {
  __shared__ float t[32][33];
  const int x0 = blockIdx.x * 32, y0 = blockIdx.y * 32;
  const int tx = threadIdx.x, ty = threadIdx.y;   // block (32,8)
#pragma unroll
  for (int i = 0; i < 4; ++i)
    t[ty + i * 8][tx] = in[(long)(y0 + ty + i * 8) * C + x0 + tx];
  __syncthreads();
#pragma unroll
  for (int i = 0; i < 4; ++i)
    out[(long)(x0 + ty + i * 8) * R + y0 + tx] = f2bf(t[tx][ty + i * 8]);
}

struct TW4 {
  const float* in0; const float* in1; const float* in2; const float* in3;
  ushort_t* o0; ushort_t* o1; ushort_t* o2; ushort_t* o3;
};
__global__ void transw4_kernel(TW4 p) {
  const float* in; ushort_t* out;
  switch (blockIdx.z) {
    case 0:  in = p.in0; out = p.o0; break;
    case 1:  in = p.in1; out = p.o1; break;
    case 2:  in = p.in2; out = p.o2; break;
    default: in = p.in3; out = p.o3; break;
  }
  __shared__ float t[32][33];
  const int x0 = blockIdx.x * 32, y0 = blockIdx.y * 32;
  const int tx = threadIdx.x, ty = threadIdx.y;   // block (32,8)
#pragma unroll
  for (int i = 0; i < 4; ++i)
    t[ty + i * 8][tx] = in[(long)(y0 + ty + i * 8) * 512 + x0 + tx];
  __syncthreads();
#pragma unroll
  for (int i = 0; i < 4; ++i)
    out[(long)(x0 + ty + i * 8) * 512 + y0 + tx] = f2bf(t[tx][ty + i * 8]);
}

// ---------- f32 -> bf16 elementwise (4/thread) ----------
__global__ void tobf_kernel(const float* __restrict__ in, ushort_t* __restrict__ out, int n4) {
  int i = blockIdx.x * blockDim.x + threadIdx.x;
  if (i >= n4) return;
  f32x4 v = ((const f32x4*)in)[i];
  u32x2 o;
  o[0] = (unsigned)f2bf(v[0]) | ((unsigned)f2bf(v[1]) << 16);
  o[1] = (unsigned)f2bf(v[2]) | ((unsigned)f2bf(v[3]) << 16);
  ((u32x2*)out)[i] = o;
}

// ---------- concat q/k/v biases into one [1536] vector ----------
__global__ void biascat_kernel(const float* __restrict__ bq, const float* __restrict__ bk,
                               const float* __restrict__ bv, float* __restrict__ o) {
  const int i = blockIdx.x * blockDim.x + threadIdx.x;
  if (i >= 1536) return;
  o[i] = (i < 512) ? bq[i] : ((i < 1024) ? bk[i - 512] : bv[i - 1024]);
}

// ---------- LayerNorm: f32 in -> bf16 out, one wave per row of 512 ----------
__global__ __launch_bounds__(256)
void ln_kernel(const float* __restrict__ x, const float* __restrict__ g,
               const float* __restrict__ b, ushort_t* __restrict__ out) {
  const int row  = blockIdx.x * 4 + (threadIdx.x >> 6);
  const int lane = threadIdx.x & 63;
  const float* xr = x + (long)row * DD + lane * 8;
  float v[8];
  *(f32x4*)&v[0] = *(const f32x4*)&xr[0];
  *(f32x4*)&v[4] = *(const f32x4*)&xr[4];
  float s = 0.f, sq = 0.f;
#pragma unroll
  for (int i = 0; i < 8; ++i) { s += v[i]; sq += v[i] * v[i]; }
#pragma unroll
  for (int o = 1; o < 64; o <<= 1) { s += __shfl_xor(s, o); sq += __shfl_xor(sq, o); }
  const float mu   = s * (1.f / 512.f);
  const float var  = sq * (1.f / 512.f) - mu * mu;
  const float rstd = rsqrtf(var + 1e-6f);
  const float* gp = g + lane * 8;
  const float* bp = b + lane * 8;
  u32x4 o8;
#pragma unroll
  for (int u = 0; u < 4; ++u) {
    unsigned int lo = f2bf((v[2 * u]     - mu) * rstd * gp[2 * u]     + bp[2 * u]);
    unsigned int hi = f2bf((v[2 * u + 1] - mu) * rstd * gp[2 * u + 1] + bp[2 * u + 1]);
    o8[u] = lo | (hi << 16);
  }
  *(u32x4*)(out + (long)row * DD + lane * 8) = o8;
}

// ==================== GEMM kernels (T2 XOR-swizzled LDS, single-buffer, T1 XCD swizzle) ====

// ---------- bf16 MFMA GEMM 128x128 tile (1D grid, XCD-banded) ----------
// EPI 0: bf16 (bias); 1: bf16 (bias+relu); 2: f32 (bias+residual);
// EPI 3: fp8 kvi out (bias); EPI 4: split qkv -> q bf16 (c<512), k|v fp8 kvi (c>=512)
template <int EPI>
__global__ __launch_bounds__(256, 4)
void gemm_kernel(const ushort_t* __restrict__ A, const ushort_t* __restrict__ Bt,
                 const float* __restrict__ bias, const float* res,
                 float* outF, ushort_t* outB, unsigned char* out8, int M, int N, int K) {
  __shared__ __align__(16) ushort_t sA[128 * 64];
  __shared__ __align__(16) ushort_t sB[128 * 64];
  const int tid  = threadIdx.x;
  const int lane = tid & 63;
  const int w    = tid >> 6;
  const int wr   = w >> 1, wc = w & 1;
  int brc, bcc;
  xcd_rc(blockIdx.x, M >> 7, N >> 7, brc, bcc);
  const long brow = (long)brc * 128;
  const long bcol = (long)bcc * 128;
  const int r16 = lane & 15;
  const int cq  = lane >> 4;                  // 16B-chunk quarter 0..3
  f32x4 acc[4][4] = {};

  for (int k0 = 0; k0 < K; k0 += 64) {
    __syncthreads();
#pragma unroll
    for (int i = 0; i < 4; ++i) {
      const int c   = i * 256 + tid;
      const int wb  = i * 256 + (tid & ~63);  // wave-uniform chunk base (linear LDS dest)
      const int row = c >> 3;
      const int col = ((c & 7) ^ (row & 7)) << 3;   // pre-swizzled source column
      gload_lds16(A  + (brow + row) * (long)K + k0 + col, &sA[(long)wb * 8]);
      gload_lds16(Bt + (bcol + row) * (long)K + k0 + col, &sB[(long)wb * 8]);
    }
    __syncthreads();
#pragma unroll
    for (int kkc = 0; kkc < 8; kkc += 4) {    // kkc: 0 -> k 0..31, 4 -> k 32..63
      u32x4 af[4], bfr[4];
#pragma unroll
      for (int i = 0; i < 4; ++i) {
        const int row = wr * 64 + i * 16 + r16;
        af[i] = *(const u32x4*)&sA[row * 64 + (((kkc + cq) ^ (row & 7)) << 3)];
      }
#pragma unroll
      for (int j = 0; j < 4; ++j) {
        const int row = wc * 64 + j * 16 + r16;
        bfr[j] = *(const u32x4*)&sB[row * 64 + (((kkc + cq) ^ (row & 7)) << 3)];
      }
#pragma unroll
      for (int i = 0; i < 4; ++i)
#pragma unroll
        for (int j = 0; j < 4; ++j)
          asm("v_mfma_f32_16x16x32_bf16 %0, %1, %2, %0"
              : "+v"(acc[i][j]) : "v"(af[i]), "v"(bfr[j]));
    }
  }
  asm volatile("s_nop 7\n\ts_nop 7\n\ts_nop 7" ::);  // MFMA->VALU hazard guard

  const long orow = brow + wr * 64;
  const long ocol = bcol + wc * 64;
#pragma unroll
  for (int j = 0; j < 4; ++j) {
    const long c  = ocol + j * 16 + r16;
    const float bv = bias[c];
#pragma unroll
    for (int i = 0; i < 4; ++i) {
      const long r0 = orow + i * 16 + ((lane >> 4) << 2);
#pragma unroll
      for (int r = 0; r < 4; ++r) {
        float v = acc[i][j][r] + bv;
        const long row = r0 + r;
        if (EPI == 0)      outB[row * (long)N + c] = f2bf(v);
        else if (EPI == 1) outB[row * (long)N + c] = f2bf(fmaxf(v, 0.f));
        else if (EPI == 2) outF[row * (long)N + c] = v + res[row * (long)N + c];
        else if (EPI == 3) store_kv(out8, row, (int)c, v);
        else {  // EPI 4: qkv split
          if (c < 512) outB[row * 512 + c] = f2bf(v);
          else         store_kv(out8, row, (int)c - 512, v);
        }
      }
    }
  }
}

// ---------- bf16 MFMA GEMM 64x64 tile (N <= 1024), 16KB LDS, XCD-banded ----------
template <int EPI>
__global__ __launch_bounds__(256, 8)
void gemm64b_kernel(const ushort_t* __restrict__ A, const ushort_t* __restrict__ Bt,
                    const float* __restrict__ bias, const float* res,
                    float* outF, ushort_t* outB, unsigned char* out8, int M, int N, int K) {
  __shared__ __align__(16) ushort_t sA[64 * 64];
  __shared__ __align__(16) ushort_t sB[64 * 64];
  const int tid  = threadIdx.x;
  const int lane = tid & 63;
  const int w    = tid >> 6;
  const int wr   = w >> 1, wc = w & 1;     // 2x2 waves, each owns 32x32
  int brc, bcc;
  xcd_rc(blockIdx.x, M >> 6, N >> 6, brc, bcc);
  const long brow = (long)brc * 64;
  const long bcol = (long)bcc * 64;
  const int r16 = lane & 15;
  const int cq  = lane >> 4;
  f32x4 acc[2][2] = {};

  for (int k0 = 0; k0 < K; k0 += 64) {
    __syncthreads();
#pragma unroll
    for (int i = 0; i < 2; ++i) {
      const int c   = i * 256 + tid;
      const int wb  = i * 256 + (tid & ~63);
      const int row = c >> 3;
      const int col = ((c & 7) ^ (row & 7)) << 3;
      gload_lds16(A  + (brow + row) * (long)K + k0 + col, &sA[(long)wb * 8]);
      gload_lds16(Bt + (bcol + row) * (long)K + k0 + col, &sB[(long)wb * 8]);
    }
    __syncthreads();
#pragma unroll
    for (int kkc = 0; kkc < 8; kkc += 4) {
      u32x4 af[2], bfr[2];
#pragma unroll
      for (int i = 0; i < 2; ++i) {
        const int row = wr * 32 + i * 16 + r16;
        af[i] = *(const u32x4*)&sA[row * 64 + (((kkc + cq) ^ (row & 7)) << 3)];
      }
#pragma unroll
      for (int j = 0; j < 2; ++j) {
        const int row = wc * 32 + j * 16 + r16;
        bfr[j] = *(const u32x4*)&sB[row * 64 + (((kkc + cq) ^ (row & 7)) << 3)];
      }
#pragma unroll
      for (int i = 0; i < 2; ++i)
#pragma unroll
        for (int j = 0; j < 2; ++j)
          asm("v_mfma_f32_16x16x32_bf16 %0, %1, %2, %0"
              : "+v"(acc[i][j]) : "v"(af[i]), "v"(bfr[j]));
    }
  }
  asm volatile("s_nop 7\n\ts_nop 7\n\ts_nop 7" ::);

  const long orow = brow + wr * 32;
  const long ocol = bcol + wc * 32;
#pragma unroll
  for (int j = 0; j < 2; ++j) {
    const long c  = ocol + j * 16 + r16;
    const float bv = bias[c];
#pragma unroll
    for (int i = 0; i < 2; ++i) {
      const long r0 = orow + i * 16 + ((lane >> 4) << 2);
#pragma unroll
      for (int r = 0; r < 4; ++r) {
        float v = acc[i][j][r] + bv;
        const long row = r0 + r;
        if (EPI == 0)      outB[row * (long)N + c] = f2bf(v);
        else if (EPI == 1) outB[row * (long)N + c] = f2bf(fmaxf(v, 0.f));
        else if (EPI == 2) outF[row * (long)N + c] = v + res[row * (long)N + c];
        else               store_kv(out8, row, (int)c, v);   // EPI 3: kvi
      }
    }
  }
}

// ---------- CSR build: single-pass counting sort by dst ----------
__global__ void zero_kernel(int* p, int n) {
  int i = blockIdx.x * blockDim.x + threadIdx.x;
  if (i < n) p[i] = 0;
}
__global__ void hist2_kernel(const int* __restrict__ d0, const int* __restrict__ d1,
                             int* __restrict__ counts2, int E) {
  const int* d = blockIdx.y ? d1 : d0;
  int* c = counts2 + blockIdx.y * 8192;
  for (int e = blockIdx.x * blockDim.x + threadIdx.x; e < E; e += gridDim.x * blockDim.x)
    atomicAdd(&c[d[e]], 1);
}
template <int PER, int BINS>
__global__ void scan_kernel(const int* __restrict__ countsN, int* __restrict__ rowstartN,
                            int* __restrict__ cursorN) {
  const int* counts = countsN + blockIdx.x * BINS;
  int* rowstart = rowstartN + blockIdx.x * (BINS + 1);
  int* cursor   = cursorN + blockIdx.x * BINS;
  __shared__ int part[256];
  const int t = threadIdx.x;
  int loc[PER];
  int s = 0;
  const int base = t * PER;
#pragma unroll
  for (int i = 0; i < PER; ++i) { loc[i] = counts[base + i]; s += loc[i]; }
  part[t] = s;
  __syncthreads();
  for (int off = 1; off < 256; off <<= 1) {
    int v2 = (t >= off) ? part[t - off] : 0;
    __syncthreads();
    part[t] += v2;
    __syncthreads();
  }
  int run = part[t] - s;   // exclusive prefix
#pragma unroll
  for (int i = 0; i < PER; ++i) { rowstart[base + i] = run; cursor[base + i] = run; run += loc[i]; }
  if (t == 255) rowstart[BINS] = run;
}
__global__ void scatterD_kernel(const int* __restrict__ s0, const int* __restrict__ d0,
                                const int* __restrict__ s1, const int* __restrict__ d1,
                                int* __restrict__ cursorD2,
                                int* __restrict__ o0, int* __restrict__ o1, int E) {
  const int* s = blockIdx.y ? s1 : s0;
  const int* d = blockIdx.y ? d1 : d0;
  int* cur = cursorD2 + blockIdx.y * 8192;
  int* o = blockIdx.y ? o1 : o0;
  for (int e = blockIdx.x * blockDim.x + threadIdx.x; e < E; e += gridDim.x * blockDim.x) {
    const int p = atomicAdd(&cur[d[e]], 1);
    o[p] = s[e];
  }
}

// ---------- graph attention: one wave per dst, interleaved fp8 kv (1 dwordx4/edge/lane) ----
#define ATT_LOADI(SD, EB)                                                   \
  _Pragma("unroll") for (int jj = 0; jj < 4; ++jj) {                        \
    int e_ = (EB) + jj;                                                     \
    SD[jj] = srcs[e_ < e1 ? e_ : e1 - 1];                                   \
  }
#define ATT_LOADG(KV, SD)                                                   \
  _Pragma("unroll") for (int jj = 0; jj < 4; ++jj)                          \
    KV[jj] = *(const u32x4*)(kvb + (long)SD[jj] * 1024 + boff);
#define ATT_EDGE(KV, VALID)                                                 \
  {                                                                         \
    f32x2 d2_ = {0.f, 0.f};                                                 \
    d2_ += (f32x2)__builtin_amdgcn_cvt_pk_f32_fp8((KV)[0], false) * q2[0];  \
    d2_ += (f32x2)__builtin_amdgcn_cvt_pk_f32_fp8((KV)[0], true)  * q2[1];  \
    d2_ += (f32x2)__builtin_amdgcn_cvt_pk_f32_fp8((KV)[1], false) * q2[2];  \
    d2_ += (f32x2)__builtin_amdgcn_cvt_pk_f32_fp8((KV)[1], true)  * q2[3];  \
    float dot_ = d2_[0] + d2_[1];                                           \
    dot_ += __shfl_xor(dot_, 1);                                            \
    dot_ += __shfl_xor(dot_, 2);                                            \
    dot_ += __shfl_xor(dot_, 4);                                            \
    float sc_ = __expf(fminf(fmaxf(dot_ * 0.125f, -10.f), 10.f));           \
    sc_ = (VALID) ? sc_ : 0.f;                                              \
    z += sc_;                                                               \
    const f32x2 s2_ = {sc_, sc_};                                           \
    av[0] += s2_ * (f32x2)__builtin_amdgcn_cvt_pk_f32_fp8((KV)[2], false);  \
    av[1] += s2_ * (f32x2)__builtin_amdgcn_cvt_pk_f32_fp8((KV)[2], true);   \
    av[2] += s2_ * (f32x2)__builtin_amdgcn_cvt_pk_f32_fp8((KV)[3], false);  \
    av[3] += s2_ * (f32x2)__builtin_amdgcn_cvt_pk_f32_fp8((KV)[3], true);   \
  }
#define ATT_GROUP(GB, KV4)                                                  \
  _Pragma("unroll") for (int jj = 0; jj < 4; ++jj) {                        \
    ATT_EDGE(KV4[jj], ((GB) + jj < n))                                      \
  }

__global__ __launch_bounds__(256)
void attend_kernel(const int* __restrict__ rowstart, const int* __restrict__ srcs,
                   const ushort_t* __restrict__ qb,
                   const unsigned char* __restrict__ kvb,   // kvi [node][1024B]
                   ushort_t* __restrict__ ob) {
  const int d    = blockIdx.x * 4 + (threadIdx.x >> 6);
  const int lane = threadIdx.x & 63;           // lane covers dims lane*8..+7; head = lane>>3
  const int boff = lane * 16;                  // one 16B [k8|v8] unit per lane
  const int e0 = rowstart[d], e1 = rowstart[d + 1];
  const int n  = e1 - e0;
  const u32x4 qv = *(const u32x4*)(qb + (long)d * DD + lane * 8);
  f32x2 q2[4];
#pragma unroll
  for (int u = 0; u < 4; ++u) q2[u] = f32x2{bflo(qv[u]), bfhi(qv[u])};
  f32x2 av[4] = {};
  float z = 0.f;
  if (n > 0) {
    int sA4[4], sB4[4];
    u32x4 kvA[4], kvB[4];
    ATT_LOADI(sA4, e0);
    ATT_LOADI(sB4, e0 + 4);
    ATT_LOADG(kvA, sA4);
    const int ng = (n + 3) >> 2;
    const int NG = (ng + 1) & ~1;            // even # of groups; tail masked by sc=0
    for (int g = 0; g < NG; g += 2) {
      ATT_LOADG(kvB, sB4);                   // issue group g+1 gathers
      ATT_LOADI(sA4, e0 + (g + 2) * 4);      // indices for group g+2
      ATT_GROUP(g * 4, kvA)                  // compute group g
      ATT_LOADG(kvA, sA4);                   // issue group g+2 gathers
      ATT_LOADI(sB4, e0 + (g + 3) * 4);      // indices for group g+3
      ATT_GROUP((g + 1) * 4, kvB)            // compute group g+1
    }
  }
  const float inv = 1.f / z;
  u32x4 o;
#pragma unroll
  for (int u = 0; u < 4; ++u)
    o[u] = (unsigned)f2bf(av[u][0] * inv) | ((unsigned)f2bf(av[u][1] * inv) << 16);
  *(u32x4*)(ob + (long)d * DD + lane * 8) = o;
}

// ---------- host orchestration ----------
extern "C" void kernel_launch(void* const* d_in, const int* in_sizes, int n_in,
                              void* d_out, int out_size, void* d_ws, size_t ws_size,
                              hipStream_t stream) {
  const float* x    = (const float*)d_in[0];
  const float* mem  = (const float*)d_in[1];
  const float* ln0g = (const float*)d_in[2];  const float* ln0b = (const float*)d_in[3];
  const float* ln1g = (const float*)d_in[4];  const float* ln1b = (const float*)d_in[5];
  const float* ln2g = (const float*)d_in[6];  const float* ln2b = (const float*)d_in[7];
  const float* Wq = (const float*)d_in[8];   const float* bq = (const float*)d_in[9];
  const float* Wk = (const float*)d_in[10];  const float* bk = (const float*)d_in[11];
  const float* Wv = (const float*)d_in[12];  const float* bv = (const float*)d_in[13];
  const float* Wo = (const float*)d_in[14];  const float* bo = (const float*)d_in[15];
  const float* W1 = (const float*)d_in[16];  const float* b1 = (const float*)d_in[17];
  const float* W2 = (const float*)d_in[18];  const float* b2 = (const float*)d_in[19];
  const int* src_self  = (const int*)d_in[20];
  const int* dst_self  = (const int*)d_in[21];
  const int* src_cross = (const int*)d_in[22];
  const int* dst_cross = (const int*)d_in[23];
  const int E = in_sizes[20];
  float* out = (float*)d_out;

  char* wsp = (char*)d_ws;
  auto alloc = [&](size_t bytes) {
    char* p = wsp;
    wsp += (bytes + 255) & ~(size_t)255;
    return p;
  };
  ushort_t* Wqkv_t = (ushort_t*)alloc((size_t)1536 * 512 * 2);
  ushort_t* Wo_t   = (ushort_t*)alloc((size_t)512 * 512 * 2);
  ushort_t* W1_t   = (ushort_t*)alloc((size_t)DFF * DD * 2);
  ushort_t* W2_t   = (ushort_t*)alloc((size_t)DD * DFF * 2);
  float*    bqkv   = (float*)alloc(1536 * 4);
  ushort_t* h_bf   = (ushort_t*)alloc((size_t)NN * DD * 2);
  ushort_t* mem_bf = (ushort_t*)alloc((size_t)MMM * DD * 2);
  ushort_t* q_bf   = (ushort_t*)alloc((size_t)NN * DD * 2);         // q (self / cross reuse)
  unsigned char* kvi = (unsigned char*)alloc((size_t)NN * 1024);    // fp8 kv interleaved
  ushort_t* attn_bf= (ushort_t*)alloc((size_t)NN * DD * 2);
  ushort_t* ffh_bf = (ushort_t*)alloc((size_t)NN * DFF * 2);
  int* countsD   = (int*)alloc(2 * 8192 * 4);
  int* rowstartD2= (int*)alloc(2 * 8193 * 4);
  int* cursorD2  = (int*)alloc(2 * 8192 * 4);
  int* srcsA     = (int*)alloc((size_t)E * 4);
  int* srcsB     = (int*)alloc((size_t)E * 4);

  const dim3 B256(256);

  // ---- prep: weights, mem cast, both dst-CSRs (input-only deps) ----
  TW4 tw{Wq, Wk, Wv, Wo, Wqkv_t, Wqkv_t + 512 * 512, Wqkv_t + 1024 * 512, Wo_t};
  transw4_kernel<<<dim3(16, 16, 4), dim3(32, 8), 0, stream>>>(tw);
  transw_kernel<<<dim3(64, 16), dim3(32, 8), 0, stream>>>(W1, W1_t, DD, DFF);
  transw_kernel<<<dim3(16, 64), dim3(32, 8), 0, stream>>>(W2, W2_t, DFF, DD);
  biascat_kernel<<<dim3(6), B256, 0, stream>>>(bq, bk, bv, bqkv);
  tobf_kernel<<<dim3(MMM * DD / 4 / 256), B256, 0, stream>>>(mem, mem_bf, MMM * DD / 4);
  zero_kernel<<<dim3(64), B256, 0, stream>>>(countsD, 2 * 8192);
  hist2_kernel<<<dim3(256, 2), B256, 0, stream>>>(dst_self, dst_cross, countsD, E);
  scan_kernel<32, 8192><<<dim3(2), B256, 0, stream>>>(countsD, rowstartD2, cursorD2);
  scatterD_kernel<<<dim3(256, 2), B256, 0, stream>>>(src_self, dst_self, src_cross, dst_cross,
                                                     cursorD2, srcsA, srcsB, E);

  auto gemm = [&](int mode, const ushort_t* Ap, const ushort_t* Btp, const float* biasp,
                  const float* resp, float* oF, ushort_t* oB, unsigned char* o8,
                  int M_, int N_, int K_) {
    if (N_ <= 1024) {
      dim3 g((M_ / 64) * (N_ / 64));
      if (mode == 0)
        gemm64b_kernel<0><<<g, B256, 0, stream>>>(Ap, Btp, biasp, resp, oF, oB, o8, M_, N_, K_);
      else if (mode == 1)
        gemm64b_kernel<1><<<g, B256, 0, stream>>>(Ap, Btp, biasp, resp, oF, oB, o8, M_, N_, K_);
      else if (mode == 2)
        gemm64b_kernel<2><<<g, B256, 0, stream>>>(Ap, Btp, biasp, resp, oF, oB, o8, M_, N_, K_);
      else
        gemm64b_kernel<3><<<g, B256, 0, stream>>>(Ap, Btp, biasp, resp, oF, oB, o8, M_, N_, K_);
    } else {
      dim3 g((M_ / 128) * (N_ / 128));
      if (mode == 0)
        gemm_kernel<0><<<g, B256, 0, stream>>>(Ap, Btp, biasp, resp, oF, oB, o8, M_, N_, K_);
      else if (mode == 1)
        gemm_kernel<1><<<g, B256, 0, stream>>>(Ap, Btp, biasp, resp, oF, oB, o8, M_, N_, K_);
      else if (mode == 2)
        gemm_kernel<2><<<g, B256, 0, stream>>>(Ap, Btp, biasp, resp, oF, oB, o8, M_, N_, K_);
      else if (mode == 3)
        gemm_kernel<3><<<g, B256, 0, stream>>>(Ap, Btp, biasp, resp, oF, oB, o8, M_, N_, K_);
      else
        gemm_kernel<4><<<g, B256, 0, stream>>>(Ap, Btp, biasp, resp, oF, oB, o8, M_, N_, K_);
    }
  };

  // ---- sublayer 0: self-attention ----
  ln_kernel<<<dim3(NN / 4), B256, 0, stream>>>(x, ln0g, ln0b, h_bf);
  gemm(4, h_bf, Wqkv_t, bqkv, nullptr, nullptr, q_bf, kvi, NN, 1536, DD);   // q bf16 | kvi fp8
  attend_kernel<<<dim3(NN / 4), B256, 0, stream>>>(rowstartD2, srcsA, q_bf, kvi, attn_bf);
  gemm(2, attn_bf, Wo_t, bo, x, out, nullptr, nullptr, NN, DD, DD);    // out = x + attn@Wo+bo

  // ---- sublayer 1: cross-attention ----
  ln_kernel<<<dim3(NN / 4), B256, 0, stream>>>(out, ln1g, ln1b, h_bf);
  gemm(0, h_bf, Wqkv_t, bqkv, nullptr, nullptr, q_bf, nullptr, NN, 512, DD);         // q bf16
  gemm(3, mem_bf, Wqkv_t + 512 * 512, bqkv + 512, nullptr, nullptr, nullptr, kvi,
       MMM, 1024, DD);                                                 // k|v fp8 kvi (no LN)
  attend_kernel<<<dim3(NN / 4), B256, 0, stream>>>(rowstartD2 + 8193, srcsB, q_bf, kvi, attn_bf);
  gemm(2, attn_bf, Wo_t, bo, out, out, nullptr, nullptr, NN, DD, DD);  // out += attn@Wo+bo

  // ---- sublayer 2: feed-forward ----
  ln_kernel<<<dim3(NN / 4), B256, 0, stream>>>(out, ln2g, ln2b, h_bf);
  gemm(1, h_bf, W1_t, b1, nullptr, nullptr, ffh_bf, nullptr, NN, DFF, DD);   // relu, bf16 out
  gemm(2, ffh_bf, W2_t, b2, out, out, nullptr, nullptr, NN, DD, DFF);        // out += ff@W2+b2

  (void)n_in; (void)out_size; (void)ws_size; (void)in_sizes;
}

// Round 16
// 275.257 us; speedup vs baseline: 1.0642x; 1.0065x over previous
//
#include <hip/hip_runtime.h>
#include <cstdint>
#include <cstddef>

#define DEV __device__ __forceinline__

typedef __attribute__((ext_vector_type(4))) float f32x4;
typedef __attribute__((ext_vector_type(2))) float f32x2;
typedef __attribute__((ext_vector_type(4))) unsigned int u32x4;
typedef __attribute__((ext_vector_type(2))) unsigned int u32x2;
typedef unsigned short ushort_t;

constexpr int NN  = 8192;   // decoder nodes
constexpr int MMM = 8192;   // encoder memory nodes
constexpr int DD  = 512;    // d_model
constexpr int DFF = 2048;   // ff hidden

// ---------- helpers ----------
DEV unsigned short f2bf(float f) {
  unsigned int u = __builtin_bit_cast(unsigned int, f);
  u += 0x7fffu + ((u >> 16) & 1u);           // round-to-nearest-even
  return (unsigned short)(u >> 16);
}
DEV float bflo(unsigned int u) { return __builtin_bit_cast(float, u << 16); }
DEV float bfhi(unsigned int u) { return __builtin_bit_cast(float, u & 0xffff0000u); }
DEV unsigned char f2fp8(float f) {            // f32 -> OCP e4m3fn via HW (RNE, saturating)
  int p = __builtin_amdgcn_cvt_pk_fp8_f32(f, f, 0, false);
  return (unsigned char)(p & 0xff);
}

// kvi layout: [node][64 units x 16B], unit i = [k dims 8i..8i+7 (8B) | v dims 8i..8i+7 (8B)].
// One dwordx4 per lane per edge fetches both k and v fragments.
DEV void store_kv(unsigned char* kvi, long node, int cc /*0..1023: k|v*/, float val) {
  int off;
  if (cc < 512) off = ((cc >> 3) << 4) + (cc & 7);
  else { const int cv = cc - 512; off = ((cv >> 3) << 4) + 8 + (cv & 7); }
  kvi[node * 1024 + off] = f2fp8(val);
}

DEV void gload_lds16(const void* g, void* l) {
  __builtin_amdgcn_global_load_lds((__attribute__((address_space(1))) void*)g,
                                   (__attribute__((address_space(3))) void*)l,
                                   16, 0, 0);
}

// XCD-locality block swizzle: wgid%8 selects XCD (round-robin dispatch). Each XCD
// owns a contiguous band of row-panels across ALL columns.
DEV void xcd_rc(int l, int gx, int gy, int& row, int& col) {
  const int xcd = l & 7;
  const int idx = l >> 3;
  const int rpx = gx >> 3;          // row-panels per XCD
  row = xcd * rpx + idx / gy;
  col = idx % gy;
}

// ---------- weight transpose + bf16 convert: in [R][C] f32 -> out [C][R] bf16 ----------
__global__ void transw_kernel(const float* __restrict__ in, ushort_t* __restrict__ out,
                              int R, int C) {
  __shared__ float t[32][33];
  const int x0 = blockIdx.x * 32, y0 = blockIdx.y * 32;
  const int tx = threadIdx.x, ty = threadIdx.y;   // block (32,8)
#pragma unroll
  for (int i = 0; i < 4; ++i)
    t[ty + i * 8][tx] = in[(long)(y0 + ty + i * 8) * C + x0 + tx];
  __syncthreads();
#pragma unroll
  for (int i = 0; i < 4; ++i)
    out[(long)(x0 + ty + i * 8) * R + y0 + tx] = f2bf(t[tx][ty + i * 8]);
}

struct TW4 {
  const float* in0; const float* in1; const float* in2; const float* in3;
  ushort_t* o0; ushort_t* o1; ushort_t* o2; ushort_t* o3;
};
__global__ void transw4_kernel(TW4 p) {
  const float* in; ushort_t* out;
  switch (blockIdx.z) {
    case 0:  in = p.in0; out = p.o0; break;
    case 1:  in = p.in1; out = p.o1; break;
    case 2:  in = p.in2; out = p.o2; break;
    default: in = p.in3; out = p.o3; break;
  }
  __shared__ float t[32][33];
  const int x0 = blockIdx.x * 32, y0 = blockIdx.y * 32;
  const int tx = threadIdx.x, ty = threadIdx.y;   // block (32,8)
#pragma unroll
  for (int i = 0; i < 4; ++i)
    t[ty + i * 8][tx] = in[(long)(y0 + ty + i * 8) * 512 + x0 + tx];
  __syncthreads();
#pragma unroll
  for (int i = 0; i < 4; ++i)
    out[(long)(x0 + ty + i * 8) * 512 + y0 + tx] = f2bf(t[tx][ty + i * 8]);
}

// ---------- f32 -> bf16 elementwise (4/thread) ----------
__global__ void tobf_kernel(const float* __restrict__ in, ushort_t* __restrict__ out, int n4) {
  int i = blockIdx.x * blockDim.x + threadIdx.x;
  if (i >= n4) return;
  f32x4 v = ((const f32x4*)in)[i];
  u32x2 o;
  o[0] = (unsigned)f2bf(v[0]) | ((unsigned)f2bf(v[1]) << 16);
  o[1] = (unsigned)f2bf(v[2]) | ((unsigned)f2bf(v[3]) << 16);
  ((u32x2*)out)[i] = o;
}

// ---------- concat q/k/v biases into one [1536] vector ----------
__global__ void biascat_kernel(const float* __restrict__ bq, const float* __restrict__ bk,
                               const float* __restrict__ bv, float* __restrict__ o) {
  const int i = blockIdx.x * blockDim.x + threadIdx.x;
  if (i >= 1536) return;
  o[i] = (i < 512) ? bq[i] : ((i < 1024) ? bk[i - 512] : bv[i - 1024]);
}

// ---------- LayerNorm: f32 in -> bf16 out, one wave per row of 512 ----------
__global__ __launch_bounds__(256)
void ln_kernel(const float* __restrict__ x, const float* __restrict__ g,
               const float* __restrict__ b, ushort_t* __restrict__ out) {
  const int row  = blockIdx.x * 4 + (threadIdx.x >> 6);
  const int lane = threadIdx.x & 63;
  const float* xr = x + (long)row * DD + lane * 8;
  float v[8];
  *(f32x4*)&v[0] = *(const f32x4*)&xr[0];
  *(f32x4*)&v[4] = *(const f32x4*)&xr[4];
  float s = 0.f, sq = 0.f;
#pragma unroll
  for (int i = 0; i < 8; ++i) { s += v[i]; sq += v[i] * v[i]; }
#pragma unroll
  for (int o = 1; o < 64; o <<= 1) { s += __shfl_xor(s, o); sq += __shfl_xor(sq, o); }
  const float mu   = s * (1.f / 512.f);
  const float var  = sq * (1.f / 512.f) - mu * mu;
  const float rstd = rsqrtf(var + 1e-6f);
  const float* gp = g + lane * 8;
  const float* bp = b + lane * 8;
  u32x4 o8;
#pragma unroll
  for (int u = 0; u < 4; ++u) {
    unsigned int lo = f2bf((v[2 * u]     - mu) * rstd * gp[2 * u]     + bp[2 * u]);
    unsigned int hi = f2bf((v[2 * u + 1] - mu) * rstd * gp[2 * u + 1] + bp[2 * u + 1]);
    o8[u] = lo | (hi << 16);
  }
  *(u32x4*)(out + (long)row * DD + lane * 8) = o8;
}

// ==================== GEMM kernels (T2 XOR-swizzled LDS, single-buffer, T1 XCD swizzle) ====

// ---------- bf16 MFMA GEMM 128x128 tile (1D grid, XCD-banded) ----------
// EPI 0: bf16 (bias); 1: bf16 (bias+relu); 2: f32 (bias+residual);
// EPI 3: fp8 kvi out (bias); EPI 4: split qkv -> q bf16 (c<512), k|v fp8 kvi (c>=512)
template <int EPI>
__global__ __launch_bounds__(256, 4)
void gemm_kernel(const ushort_t* __restrict__ A, const ushort_t* __restrict__ Bt,
                 const float* __restrict__ bias, const float* res,
                 float* outF, ushort_t* outB, unsigned char* out8, int M, int N, int K) {
  __shared__ __align__(16) ushort_t sA[128 * 64];
  __shared__ __align__(16) ushort_t sB[128 * 64];
  const int tid  = threadIdx.x;
  const int lane = tid & 63;
  const int w    = tid >> 6;
  const int wr   = w >> 1, wc = w & 1;
  int brc, bcc;
  xcd_rc(blockIdx.x, M >> 7, N >> 7, brc, bcc);
  const long brow = (long)brc * 128;
  const long bcol = (long)bcc * 128;
  const int r16 = lane & 15;
  const int cq  = lane >> 4;                  // 16B-chunk quarter 0..3
  f32x4 acc[4][4] = {};

  for (int k0 = 0; k0 < K; k0 += 64) {
    __syncthreads();
#pragma unroll
    for (int i = 0; i < 4; ++i) {
      const int c   = i * 256 + tid;
      const int wb  = i * 256 + (tid & ~63);  // wave-uniform chunk base (linear LDS dest)
      const int row = c >> 3;
      const int col = ((c & 7) ^ (row & 7)) << 3;   // pre-swizzled source column
      gload_lds16(A  + (brow + row) * (long)K + k0 + col, &sA[(long)wb * 8]);
      gload_lds16(Bt + (bcol + row) * (long)K + k0 + col, &sB[(long)wb * 8]);
    }
    __syncthreads();
#pragma unroll
    for (int kkc = 0; kkc < 8; kkc += 4) {    // kkc: 0 -> k 0..31, 4 -> k 32..63
      u32x4 af[4], bfr[4];
#pragma unroll
      for (int i = 0; i < 4; ++i) {
        const int row = wr * 64 + i * 16 + r16;
        af[i] = *(const u32x4*)&sA[row * 64 + (((kkc + cq) ^ (row & 7)) << 3)];
      }
#pragma unroll
      for (int j = 0; j < 4; ++j) {
        const int row = wc * 64 + j * 16 + r16;
        bfr[j] = *(const u32x4*)&sB[row * 64 + (((kkc + cq) ^ (row & 7)) << 3)];
      }
#pragma unroll
      for (int i = 0; i < 4; ++i)
#pragma unroll
        for (int j = 0; j < 4; ++j)
          asm("v_mfma_f32_16x16x32_bf16 %0, %1, %2, %0"
              : "+v"(acc[i][j]) : "v"(af[i]), "v"(bfr[j]));
    }
  }
  asm volatile("s_nop 7\n\ts_nop 7\n\ts_nop 7" ::);  // MFMA->VALU hazard guard

  const long orow = brow + wr * 64;
  const long ocol = bcol + wc * 64;
#pragma unroll
  for (int j = 0; j < 4; ++j) {
    const long c  = ocol + j * 16 + r16;
    const float bv = bias[c];
#pragma unroll
    for (int i = 0; i < 4; ++i) {
      const long r0 = orow + i * 16 + ((lane >> 4) << 2);
#pragma unroll
      for (int r = 0; r < 4; ++r) {
        float v = acc[i][j][r] + bv;
        const long row = r0 + r;
        if (EPI == 0)      outB[row * (long)N + c] = f2bf(v);
        else if (EPI == 1) outB[row * (long)N + c] = f2bf(fmaxf(v, 0.f));
        else if (EPI == 2) outF[row * (long)N + c] = v + res[row * (long)N + c];
        else if (EPI == 3) store_kv(out8, row, (int)c, v);
        else {  // EPI 4: qkv split
          if (c < 512) outB[row * 512 + c] = f2bf(v);
          else         store_kv(out8, row, (int)c - 512, v);
        }
      }
    }
  }
}

// ---------- bf16 MFMA GEMM 64x64 tile (N <= 1024), 16KB LDS, XCD-banded ----------
template <int EPI>
__global__ __launch_bounds__(256, 8)
void gemm64b_kernel(const ushort_t* __restrict__ A, const ushort_t* __restrict__ Bt,
                    const float* __restrict__ bias, const float* res,
                    float* outF, ushort_t* outB, unsigned char* out8, int M, int N, int K) {
  __shared__ __align__(16) ushort_t sA[64 * 64];
  __shared__ __align__(16) ushort_t sB[64 * 64];
  const int tid  = threadIdx.x;
  const int lane = tid & 63;
  const int w    = tid >> 6;
  const int wr   = w >> 1, wc = w & 1;     // 2x2 waves, each owns 32x32
  int brc, bcc;
  xcd_rc(blockIdx.x, M >> 6, N >> 6, brc, bcc);
  const long brow = (long)brc * 64;
  const long bcol = (long)bcc * 64;
  const int r16 = lane & 15;
  const int cq  = lane >> 4;
  f32x4 acc[2][2] = {};

  for (int k0 = 0; k0 < K; k0 += 64) {
    __syncthreads();
#pragma unroll
    for (int i = 0; i < 2; ++i) {
      const int c   = i * 256 + tid;
      const int wb  = i * 256 + (tid & ~63);
      const int row = c >> 3;
      const int col = ((c & 7) ^ (row & 7)) << 3;
      gload_lds16(A  + (brow + row) * (long)K + k0 + col, &sA[(long)wb * 8]);
      gload_lds16(Bt + (bcol + row) * (long)K + k0 + col, &sB[(long)wb * 8]);
    }
    __syncthreads();
#pragma unroll
    for (int kkc = 0; kkc < 8; kkc += 4) {
      u32x4 af[2], bfr[2];
#pragma unroll
      for (int i = 0; i < 2; ++i) {
        const int row = wr * 32 + i * 16 + r16;
        af[i] = *(const u32x4*)&sA[row * 64 + (((kkc + cq) ^ (row & 7)) << 3)];
      }
#pragma unroll
      for (int j = 0; j < 2; ++j) {
        const int row = wc * 32 + j * 16 + r16;
        bfr[j] = *(const u32x4*)&sB[row * 64 + (((kkc + cq) ^ (row & 7)) << 3)];
      }
#pragma unroll
      for (int i = 0; i < 2; ++i)
#pragma unroll
        for (int j = 0; j < 2; ++j)
          asm("v_mfma_f32_16x16x32_bf16 %0, %1, %2, %0"
              : "+v"(acc[i][j]) : "v"(af[i]), "v"(bfr[j]));
    }
  }
  asm volatile("s_nop 7\n\ts_nop 7\n\ts_nop 7" ::);

  const long orow = brow + wr * 32;
  const long ocol = bcol + wc * 32;
#pragma unroll
  for (int j = 0; j < 2; ++j) {
    const long c  = ocol + j * 16 + r16;
    const float bv = bias[c];
#pragma unroll
    for (int i = 0; i < 2; ++i) {
      const long r0 = orow + i * 16 + ((lane >> 4) << 2);
#pragma unroll
      for (int r = 0; r < 4; ++r) {
        float v = acc[i][j][r] + bv;
        const long row = r0 + r;
        if (EPI == 0)      outB[row * (long)N + c] = f2bf(v);
        else if (EPI == 1) outB[row * (long)N + c] = f2bf(fmaxf(v, 0.f));
        else if (EPI == 2) outF[row * (long)N + c] = v + res[row * (long)N + c];
        else               store_kv(out8, row, (int)c, v);   // EPI 3: kvi
      }
    }
  }
}

// ---------- CSR build: single-pass counting sort by dst ----------
__global__ void zero_kernel(int* p, int n) {
  int i = blockIdx.x * blockDim.x + threadIdx.x;
  if (i < n) p[i] = 0;
}
__global__ void hist2_kernel(const int* __restrict__ d0, const int* __restrict__ d1,
                             int* __restrict__ counts2, int E) {
  const int* d = blockIdx.y ? d1 : d0;
  int* c = counts2 + blockIdx.y * 8192;
  for (int e = blockIdx.x * blockDim.x + threadIdx.x; e < E; e += gridDim.x * blockDim.x)
    atomicAdd(&c[d[e]], 1);
}
template <int PER, int BINS>
__global__ void scan_kernel(const int* __restrict__ countsN, int* __restrict__ rowstartN,
                            int* __restrict__ cursorN) {
  const int* counts = countsN + blockIdx.x * BINS;
  int* rowstart = rowstartN + blockIdx.x * (BINS + 1);
  int* cursor   = cursorN + blockIdx.x * BINS;
  __shared__ int part[256];
  const int t = threadIdx.x;
  int loc[PER];
  int s = 0;
  const int base = t * PER;
#pragma unroll
  for (int i = 0; i < PER; ++i) { loc[i] = counts[base + i]; s += loc[i]; }
  part[t] = s;
  __syncthreads();
  for (int off = 1; off < 256; off <<= 1) {
    int v2 = (t >= off) ? part[t - off] : 0;
    __syncthreads();
    part[t] += v2;
    __syncthreads();
  }
  int run = part[t] - s;   // exclusive prefix
#pragma unroll
  for (int i = 0; i < PER; ++i) { rowstart[base + i] = run; cursor[base + i] = run; run += loc[i]; }
  if (t == 255) rowstart[BINS] = run;
}
// dst-range-partitioned scatter: block handles only dsts in its range (blockIdx.x & 7).
// Under round-robin block->XCD dispatch, each range's output window (~128KB contiguous)
// and cursor slice stay in ONE XCD's L2 -> no cross-fabric line ping-pong. Edge stream
// is re-read 8x (sequential, L3-served) -- cheap vs the 14x write amplification it removes.
__global__ void scatterD_kernel(const int* __restrict__ s0, const int* __restrict__ d0,
                                const int* __restrict__ s1, const int* __restrict__ d1,
                                int* __restrict__ cursorD2,
                                int* __restrict__ o0, int* __restrict__ o1, int E) {
  const int* s = blockIdx.y ? s1 : s0;
  const int* d = blockIdx.y ? d1 : d0;
  int* cur = cursorD2 + blockIdx.y * 8192;
  int* o = blockIdx.y ? o1 : o0;
  const int range  = blockIdx.x & 7;            // dst in [range*1024, range*1024+1024)
  const int group  = blockIdx.x >> 3;
  const int stride = (gridDim.x >> 3) * blockDim.x;
  for (int e = group * blockDim.x + threadIdx.x; e < E; e += stride) {
    const int dv = d[e];
    if ((dv >> 10) == range) {
      const int p = atomicAdd(&cur[dv], 1);
      o[p] = s[e];
    }
  }
}

// ---------- graph attention: one wave per dst, interleaved fp8 kv (1 dwordx4/edge/lane) ----
#define ATT_LOADI(SD, EB)                                                   \
  _Pragma("unroll") for (int jj = 0; jj < 4; ++jj) {                        \
    int e_ = (EB) + jj;                                                     \
    SD[jj] = srcs[e_ < e1 ? e_ : e1 - 1];                                   \
  }
#define ATT_LOADG(KV, SD)                                                   \
  _Pragma("unroll") for (int jj = 0; jj < 4; ++jj)                          \
    KV[jj] = *(const u32x4*)(kvb + (long)SD[jj] * 1024 + boff);
#define ATT_EDGE(KV, VALID)                                                 \
  {                                                                         \
    f32x2 d2_ = {0.f, 0.f};                                                 \
    d2_ += (f32x2)__builtin_amdgcn_cvt_pk_f32_fp8((KV)[0], false) * q2[0];  \
    d2_ += (f32x2)__builtin_amdgcn_cvt_pk_f32_fp8((KV)[0], true)  * q2[1];  \
    d2_ += (f32x2)__builtin_amdgcn_cvt_pk_f32_fp8((KV)[1], false) * q2[2];  \
    d2_ += (f32x2)__builtin_amdgcn_cvt_pk_f32_fp8((KV)[1], true)  * q2[3];  \
    float dot_ = d2_[0] + d2_[1];                                           \
    dot_ += __shfl_xor(dot_, 1);                                            \
    dot_ += __shfl_xor(dot_, 2);                                            \
    dot_ += __shfl_xor(dot_, 4);                                            \
    float sc_ = __expf(fminf(fmaxf(dot_ * 0.125f, -10.f), 10.f));           \
    sc_ = (VALID) ? sc_ : 0.f;                                              \
    z += sc_;                                                               \
    const f32x2 s2_ = {sc_, sc_};                                           \
    av[0] += s2_ * (f32x2)__builtin_amdgcn_cvt_pk_f32_fp8((KV)[2], false);  \
    av[1] += s2_ * (f32x2)__builtin_amdgcn_cvt_pk_f32_fp8((KV)[2], true);   \
    av[2] += s2_ * (f32x2)__builtin_amdgcn_cvt_pk_f32_fp8((KV)[3], false);  \
    av[3] += s2_ * (f32x2)__builtin_amdgcn_cvt_pk_f32_fp8((KV)[3], true);   \
  }
#define ATT_GROUP(GB, KV4)                                                  \
  _Pragma("unroll") for (int jj = 0; jj < 4; ++jj) {                        \
    ATT_EDGE(KV4[jj], ((GB) + jj < n))                                      \
  }

__global__ __launch_bounds__(256)
void attend_kernel(const int* __restrict__ rowstart, const int* __restrict__ srcs,
                   const ushort_t* __restrict__ qb,
                   const unsigned char* __restrict__ kvb,   // kvi [node][1024B]
                   ushort_t* __restrict__ ob) {
  const int d    = blockIdx.x * 4 + (threadIdx.x >> 6);
  const int lane = threadIdx.x & 63;           // lane covers dims lane*8..+7; head = lane>>3
  const int boff = lane * 16;                  // one 16B [k8|v8] unit per lane
  const int e0 = rowstart[d], e1 = rowstart[d + 1];
  const int n  = e1 - e0;
  const u32x4 qv = *(const u32x4*)(qb + (long)d * DD + lane * 8);
  f32x2 q2[4];
#pragma unroll
  for (int u = 0; u < 4; ++u) q2[u] = f32x2{bflo(qv[u]), bfhi(qv[u])};
  f32x2 av[4] = {};
  float z = 0.f;
  if (n > 0) {
    int sA4[4], sB4[4];
    u32x4 kvA[4], kvB[4];
    ATT_LOADI(sA4, e0);
    ATT_LOADI(sB4, e0 + 4);
    ATT_LOADG(kvA, sA4);
    const int ng = (n + 3) >> 2;
    const int NG = (ng + 1) & ~1;            // even # of groups; tail masked by sc=0
    for (int g = 0; g < NG; g += 2) {
      ATT_LOADG(kvB, sB4);                   // issue group g+1 gathers
      ATT_LOADI(sA4, e0 + (g + 2) * 4);      // indices for group g+2
      ATT_GROUP(g * 4, kvA)                  // compute group g
      ATT_LOADG(kvA, sA4);                   // issue group g+2 gathers
      ATT_LOADI(sB4, e0 + (g + 3) * 4);      // indices for group g+3
      ATT_GROUP((g + 1) * 4, kvB)            // compute group g+1
    }
  }
  const float inv = 1.f / z;
  u32x4 o;
#pragma unroll
  for (int u = 0; u < 4; ++u)
    o[u] = (unsigned)f2bf(av[u][0] * inv) | ((unsigned)f2bf(av[u][1] * inv) << 16);
  *(u32x4*)(ob + (long)d * DD + lane * 8) = o;
}

// ---------- host orchestration ----------
extern "C" void kernel_launch(void* const* d_in, const int* in_sizes, int n_in,
                              void* d_out, int out_size, void* d_ws, size_t ws_size,
                              hipStream_t stream) {
  const float* x    = (const float*)d_in[0];
  const float* mem  = (const float*)d_in[1];
  const float* ln0g = (const float*)d_in[2];  const float* ln0b = (const float*)d_in[3];
  const float* ln1g = (const float*)d_in[4];  const float* ln1b = (const float*)d_in[5];
  const float* ln2g = (const float*)d_in[6];  const float* ln2b = (const float*)d_in[7];
  const float* Wq = (const float*)d_in[8];   const float* bq = (const float*)d_in[9];
  const float* Wk = (const float*)d_in[10];  const float* bk = (const float*)d_in[11];
  const float* Wv = (const float*)d_in[12];  const float* bv = (const float*)d_in[13];
  const float* Wo = (const float*)d_in[14];  const float* bo = (const float*)d_in[15];
  const float* W1 = (const float*)d_in[16];  const float* b1 = (const float*)d_in[17];
  const float* W2 = (const float*)d_in[18];  const float* b2 = (const float*)d_in[19];
  const int* src_self  = (const int*)d_in[20];
  const int* dst_self  = (const int*)d_in[21];
  const int* src_cross = (const int*)d_in[22];
  const int* dst_cross = (const int*)d_in[23];
  const int E = in_sizes[20];
  float* out = (float*)d_out;

  char* wsp = (char*)d_ws;
  auto alloc = [&](size_t bytes) {
    char* p = wsp;
    wsp += (bytes + 255) & ~(size_t)255;
    return p;
  };
  ushort_t* Wqkv_t = (ushort_t*)alloc((size_t)1536 * 512 * 2);
  ushort_t* Wo_t   = (ushort_t*)alloc((size_t)512 * 512 * 2);
  ushort_t* W1_t   = (ushort_t*)alloc((size_t)DFF * DD * 2);
  ushort_t* W2_t   = (ushort_t*)alloc((size_t)DD * DFF * 2);
  float*    bqkv   = (float*)alloc(1536 * 4);
  ushort_t* h_bf   = (ushort_t*)alloc((size_t)NN * DD * 2);
  ushort_t* mem_bf = (ushort_t*)alloc((size_t)MMM * DD * 2);
  ushort_t* q_bf   = (ushort_t*)alloc((size_t)NN * DD * 2);         // q (self / cross reuse)
  unsigned char* kvi = (unsigned char*)alloc((size_t)NN * 1024);    // fp8 kv interleaved
  ushort_t* attn_bf= (ushort_t*)alloc((size_t)NN * DD * 2);
  ushort_t* ffh_bf = (ushort_t*)alloc((size_t)NN * DFF * 2);
  int* countsD   = (int*)alloc(2 * 8192 * 4);
  int* rowstartD2= (int*)alloc(2 * 8193 * 4);
  int* cursorD2  = (int*)alloc(2 * 8192 * 4);
  int* srcsA     = (int*)alloc((size_t)E * 4);
  int* srcsB     = (int*)alloc((size_t)E * 4);

  const dim3 B256(256);

  // ---- prep: weights, mem cast, both dst-CSRs (input-only deps) ----
  TW4 tw{Wq, Wk, Wv, Wo, Wqkv_t, Wqkv_t + 512 * 512, Wqkv_t + 1024 * 512, Wo_t};
  transw4_kernel<<<dim3(16, 16, 4), dim3(32, 8), 0, stream>>>(tw);
  transw_kernel<<<dim3(64, 16), dim3(32, 8), 0, stream>>>(W1, W1_t, DD, DFF);
  transw_kernel<<<dim3(16, 64), dim3(32, 8), 0, stream>>>(W2, W2_t, DFF, DD);
  biascat_kernel<<<dim3(6), B256, 0, stream>>>(bq, bk, bv, bqkv);
  tobf_kernel<<<dim3(MMM * DD / 4 / 256), B256, 0, stream>>>(mem, mem_bf, MMM * DD / 4);
  zero_kernel<<<dim3(64), B256, 0, stream>>>(countsD, 2 * 8192);
  hist2_kernel<<<dim3(256, 2), B256, 0, stream>>>(dst_self, dst_cross, countsD, E);
  scan_kernel<32, 8192><<<dim3(2), B256, 0, stream>>>(countsD, rowstartD2, cursorD2);
  scatterD_kernel<<<dim3(256, 2), B256, 0, stream>>>(src_self, dst_self, src_cross, dst_cross,
                                                     cursorD2, srcsA, srcsB, E);

  auto gemm = [&](int mode, const ushort_t* Ap, const ushort_t* Btp, const float* biasp,
                  const float* resp, float* oF, ushort_t* oB, unsigned char* o8,
                  int M_, int N_, int K_) {
    if (N_ <= 1024) {
      dim3 g((M_ / 64) * (N_ / 64));
      if (mode == 0)
        gemm64b_kernel<0><<<g, B256, 0, stream>>>(Ap, Btp, biasp, resp, oF, oB, o8, M_, N_, K_);
      else if (mode == 1)
        gemm64b_kernel<1><<<g, B256, 0, stream>>>(Ap, Btp, biasp, resp, oF, oB, o8, M_, N_, K_);
      else if (mode == 2)
        gemm64b_kernel<2><<<g, B256, 0, stream>>>(Ap, Btp, biasp, resp, oF, oB, o8, M_, N_, K_);
      else
        gemm64b_kernel<3><<<g, B256, 0, stream>>>(Ap, Btp, biasp, resp, oF, oB, o8, M_, N_, K_);
    } else {
      dim3 g((M_ / 128) * (N_ / 128));
      if (mode == 0)
        gemm_kernel<0><<<g, B256, 0, stream>>>(Ap, Btp, biasp, resp, oF, oB, o8, M_, N_, K_);
      else if (mode == 1)
        gemm_kernel<1><<<g, B256, 0, stream>>>(Ap, Btp, biasp, resp, oF, oB, o8, M_, N_, K_);
      else if (mode == 2)
        gemm_kernel<2><<<g, B256, 0, stream>>>(Ap, Btp, biasp, resp, oF, oB, o8, M_, N_, K_);
      else if (mode == 3)
        gemm_kernel<3><<<g, B256, 0, stream>>>(Ap, Btp, biasp, resp, oF, oB, o8, M_, N_, K_);
      else
        gemm_kernel<4><<<g, B256, 0, stream>>>(Ap, Btp, biasp, resp, oF, oB, o8, M_, N_, K_);
    }
  };

  // ---- sublayer 0: self-attention ----
  ln_kernel<<<dim3(NN / 4), B256, 0, stream>>>(x, ln0g, ln0b, h_bf);
  gemm(4, h_bf, Wqkv_t, bqkv, nullptr, nullptr, q_bf, kvi, NN, 1536, DD);   // q bf16 | kvi fp8
  attend_kernel<<<dim3(NN / 4), B256, 0, stream>>>(rowstartD2, srcsA, q_bf, kvi, attn_bf);
  gemm(2, attn_bf, Wo_t, bo, x, out, nullptr, nullptr, NN, DD, DD);    // out = x + attn@Wo+bo

  // ---- sublayer 1: cross-attention ----
  ln_kernel<<<dim3(NN / 4), B256, 0, stream>>>(out, ln1g, ln1b, h_bf);
  gemm(0, h_bf, Wqkv_t, bqkv, nullptr, nullptr, q_bf, nullptr, NN, 512, DD);         // q bf16
  gemm(3, mem_bf, Wqkv_t + 512 * 512, bqkv + 512, nullptr, nullptr, nullptr, kvi,
       MMM, 1024, DD);                                                 // k|v fp8 kvi (no LN)
  attend_kernel<<<dim3(NN / 4), B256, 0, stream>>>(rowstartD2 + 8193, srcsB, q_bf, kvi, attn_bf);
  gemm(2, attn_bf, Wo_t, bo, out, out, nullptr, nullptr, NN, DD, DD);  // out += attn@Wo+bo

  // ---- sublayer 2: feed-forward ----
  ln_kernel<<<dim3(NN / 4), B256, 0, stream>>>(out, ln2g, ln2b, h_bf);
  gemm(1, h_bf, W1_t, b1, nullptr, nullptr, ffh_bf, nullptr, NN, DFF, DD);   // relu, bf16 out
  gemm(2, ffh_bf, W2_t, b2, out, out, nullptr, nullptr, NN, DD, DFF);        // out += ff@W2+b2

  (void)n_in; (void)out_size; (void)ws_size; (void)in_sizes;
}

// Round 17
// 271.862 us; speedup vs baseline: 1.0775x; 1.0125x over previous
//
#include <hip/hip_runtime.h>
#include <cstdint>
#include <cstddef>

#define DEV __device__ __forceinline__

typedef __attribute__((ext_vector_type(4))) float f32x4;
typedef __attribute__((ext_vector_type(2))) float f32x2;
typedef __attribute__((ext_vector_type(4))) unsigned int u32x4;
typedef __attribute__((ext_vector_type(2))) unsigned int u32x2;
typedef unsigned short ushort_t;

constexpr int NN  = 8192;   // decoder nodes
constexpr int MMM = 8192;   // encoder memory nodes
constexpr int DD  = 512;    // d_model
constexpr int DFF = 2048;   // ff hidden

// ---------- helpers ----------
DEV unsigned short f2bf(float f) {
  unsigned int u = __builtin_bit_cast(unsigned int, f);
  u += 0x7fffu + ((u >> 16) & 1u);           // round-to-nearest-even
  return (unsigned short)(u >> 16);
}
DEV float bflo(unsigned int u) { return __builtin_bit_cast(float, u << 16); }
DEV float bfhi(unsigned int u) { return __builtin_bit_cast(float, u & 0xffff0000u); }
DEV unsigned char f2fp8(float f) {            // f32 -> OCP e4m3fn via HW (RNE, saturating)
  int p = __builtin_amdgcn_cvt_pk_fp8_f32(f, f, 0, false);
  return (unsigned char)(p & 0xff);
}

// kvi layout: [node][64 units x 16B], unit i = [k dims 8i..8i+7 (8B) | v dims 8i..8i+7 (8B)].
// One dwordx4 per lane per edge fetches both k and v fragments.
DEV void store_kv(unsigned char* kvi, long node, int cc /*0..1023: k|v*/, float val) {
  int off;
  if (cc < 512) off = ((cc >> 3) << 4) + (cc & 7);
  else { const int cv = cc - 512; off = ((cv >> 3) << 4) + 8 + (cv & 7); }
  kvi[node * 1024 + off] = f2fp8(val);
}

DEV void gload_lds16(const void* g, void* l) {
  __builtin_amdgcn_global_load_lds((__attribute__((address_space(1))) void*)g,
                                   (__attribute__((address_space(3))) void*)l,
                                   16, 0, 0);
}

// XCD-locality block swizzle: wgid%8 selects XCD (round-robin dispatch). Each XCD
// owns a contiguous band of row-panels across ALL columns.
DEV void xcd_rc(int l, int gx, int gy, int& row, int& col) {
  const int xcd = l & 7;
  const int idx = l >> 3;
  const int rpx = gx >> 3;          // row-panels per XCD
  row = xcd * rpx + idx / gy;
  col = idx % gy;
}

// ---------- weight transpose + bf16 convert: in [R][C] f32 -> out [C][R] bf16 ----------
__global__ void transw_kernel(const float* __restrict__ in, ushort_t* __restrict__ out,
                              int R, int C) {
  __shared__ float t[32][33];
  const int x0 = blockIdx.x * 32, y0 = blockIdx.y * 32;
  const int tx = threadIdx.x, ty = threadIdx.y;   // block (32,8)
#pragma unroll
  for (int i = 0; i < 4; ++i)
    t[ty + i * 8][tx] = in[(long)(y0 + ty + i * 8) * C + x0 + tx];
  __syncthreads();
#pragma unroll
  for (int i = 0; i < 4; ++i)
    out[(long)(x0 + ty + i * 8) * R + y0 + tx] = f2bf(t[tx][ty + i * 8]);
}

struct TW4 {
  const float* in0; const float* in1; const float* in2; const float* in3;
  ushort_t* o0; ushort_t* o1; ushort_t* o2; ushort_t* o3;
};
__global__ void transw4_kernel(TW4 p) {
  const float* in; ushort_t* out;
  switch (blockIdx.z) {
    case 0:  in = p.in0; out = p.o0; break;
    case 1:  in = p.in1; out = p.o1; break;
    case 2:  in = p.in2; out = p.o2; break;
    default: in = p.in3; out = p.o3; break;
  }
  __shared__ float t[32][33];
  const int x0 = blockIdx.x * 32, y0 = blockIdx.y * 32;
  const int tx = threadIdx.x, ty = threadIdx.y;   // block (32,8)
#pragma unroll
  for (int i = 0; i < 4; ++i)
    t[ty + i * 8][tx] = in[(long)(y0 + ty + i * 8) * 512 + x0 + tx];
  __syncthreads();
#pragma unroll
  for (int i = 0; i < 4; ++i)
    out[(long)(x0 + ty + i * 8) * 512 + y0 + tx] = f2bf(t[tx][ty + i * 8]);
}

// ---------- f32 -> bf16 elementwise (4/thread) ----------
__global__ void tobf_kernel(const float* __restrict__ in, ushort_t* __restrict__ out, int n4) {
  int i = blockIdx.x * blockDim.x + threadIdx.x;
  if (i >= n4) return;
  f32x4 v = ((const f32x4*)in)[i];
  u32x2 o;
  o[0] = (unsigned)f2bf(v[0]) | ((unsigned)f2bf(v[1]) << 16);
  o[1] = (unsigned)f2bf(v[2]) | ((unsigned)f2bf(v[3]) << 16);
  ((u32x2*)out)[i] = o;
}

// ---------- concat q/k/v biases into one [1536] vector ----------
__global__ void biascat_kernel(const float* __restrict__ bq, const float* __restrict__ bk,
                               const float* __restrict__ bv, float* __restrict__ o) {
  const int i = blockIdx.x * blockDim.x + threadIdx.x;
  if (i >= 1536) return;
  o[i] = (i < 512) ? bq[i] : ((i < 1024) ? bk[i - 512] : bv[i - 1024]);
}

// ---------- LayerNorm: f32 in -> bf16 out, one wave per row of 512 ----------
__global__ __launch_bounds__(256)
void ln_kernel(const float* __restrict__ x, const float* __restrict__ g,
               const float* __restrict__ b, ushort_t* __restrict__ out) {
  const int row  = blockIdx.x * 4 + (threadIdx.x >> 6);
  const int lane = threadIdx.x & 63;
  const float* xr = x + (long)row * DD + lane * 8;
  float v[8];
  *(f32x4*)&v[0] = *(const f32x4*)&xr[0];
  *(f32x4*)&v[4] = *(const f32x4*)&xr[4];
  float s = 0.f, sq = 0.f;
#pragma unroll
  for (int i = 0; i < 8; ++i) { s += v[i]; sq += v[i] * v[i]; }
#pragma unroll
  for (int o = 1; o < 64; o <<= 1) { s += __shfl_xor(s, o); sq += __shfl_xor(sq, o); }
  const float mu   = s * (1.f / 512.f);
  const float var  = sq * (1.f / 512.f) - mu * mu;
  const float rstd = rsqrtf(var + 1e-6f);
  const float* gp = g + lane * 8;
  const float* bp = b + lane * 8;
  u32x4 o8;
#pragma unroll
  for (int u = 0; u < 4; ++u) {
    unsigned int lo = f2bf((v[2 * u]     - mu) * rstd * gp[2 * u]     + bp[2 * u]);
    unsigned int hi = f2bf((v[2 * u + 1] - mu) * rstd * gp[2 * u + 1] + bp[2 * u + 1]);
    o8[u] = lo | (hi << 16);
  }
  *(u32x4*)(out + (long)row * DD + lane * 8) = o8;
}

// ==================== GEMM kernels (T2 XOR-swizzled LDS, single-buffer, T1 XCD swizzle) ====

// ---------- bf16 MFMA GEMM 128x128 tile (1D grid, XCD-banded) ----------
// EPI 0: bf16 (bias); 1: bf16 (bias+relu); 2: f32 (bias+residual);
// EPI 3: fp8 kvi out (bias); EPI 4: split qkv -> q bf16 (c<512), k|v fp8 kvi (c>=512)
template <int EPI>
__global__ __launch_bounds__(256, 4)
void gemm_kernel(const ushort_t* __restrict__ A, const ushort_t* __restrict__ Bt,
                 const float* __restrict__ bias, const float* res,
                 float* outF, ushort_t* outB, unsigned char* out8, int M, int N, int K) {
  __shared__ __align__(16) ushort_t sA[128 * 64];
  __shared__ __align__(16) ushort_t sB[128 * 64];
  const int tid  = threadIdx.x;
  const int lane = tid & 63;
  const int w    = tid >> 6;
  const int wr   = w >> 1, wc = w & 1;
  int brc, bcc;
  xcd_rc(blockIdx.x, M >> 7, N >> 7, brc, bcc);
  const long brow = (long)brc * 128;
  const long bcol = (long)bcc * 128;
  const int r16 = lane & 15;
  const int cq  = lane >> 4;                  // 16B-chunk quarter 0..3
  f32x4 acc[4][4] = {};

  for (int k0 = 0; k0 < K; k0 += 64) {
    __syncthreads();
#pragma unroll
    for (int i = 0; i < 4; ++i) {
      const int c   = i * 256 + tid;
      const int wb  = i * 256 + (tid & ~63);  // wave-uniform chunk base (linear LDS dest)
      const int row = c >> 3;
      const int col = ((c & 7) ^ (row & 7)) << 3;   // pre-swizzled source column
      gload_lds16(A  + (brow + row) * (long)K + k0 + col, &sA[(long)wb * 8]);
      gload_lds16(Bt + (bcol + row) * (long)K + k0 + col, &sB[(long)wb * 8]);
    }
    __syncthreads();
#pragma unroll
    for (int kkc = 0; kkc < 8; kkc += 4) {    // kkc: 0 -> k 0..31, 4 -> k 32..63
      u32x4 af[4], bfr[4];
#pragma unroll
      for (int i = 0; i < 4; ++i) {
        const int row = wr * 64 + i * 16 + r16;
        af[i] = *(const u32x4*)&sA[row * 64 + (((kkc + cq) ^ (row & 7)) << 3)];
      }
#pragma unroll
      for (int j = 0; j < 4; ++j) {
        const int row = wc * 64 + j * 16 + r16;
        bfr[j] = *(const u32x4*)&sB[row * 64 + (((kkc + cq) ^ (row & 7)) << 3)];
      }
#pragma unroll
      for (int i = 0; i < 4; ++i)
#pragma unroll
        for (int j = 0; j < 4; ++j)
          asm("v_mfma_f32_16x16x32_bf16 %0, %1, %2, %0"
              : "+v"(acc[i][j]) : "v"(af[i]), "v"(bfr[j]));
    }
  }
  asm volatile("s_nop 7\n\ts_nop 7\n\ts_nop 7" ::);  // MFMA->VALU hazard guard

  const long orow = brow + wr * 64;
  const long ocol = bcol + wc * 64;
#pragma unroll
  for (int j = 0; j < 4; ++j) {
    const long c  = ocol + j * 16 + r16;
    const float bv = bias[c];
#pragma unroll
    for (int i = 0; i < 4; ++i) {
      const long r0 = orow + i * 16 + ((lane >> 4) << 2);
#pragma unroll
      for (int r = 0; r < 4; ++r) {
        float v = acc[i][j][r] + bv;
        const long row = r0 + r;
        if (EPI == 0)      outB[row * (long)N + c] = f2bf(v);
        else if (EPI == 1) outB[row * (long)N + c] = f2bf(fmaxf(v, 0.f));
        else if (EPI == 2) outF[row * (long)N + c] = v + res[row * (long)N + c];
        else if (EPI == 3) store_kv(out8, row, (int)c, v);
        else {  // EPI 4: qkv split
          if (c < 512) outB[row * 512 + c] = f2bf(v);
          else         store_kv(out8, row, (int)c - 512, v);
        }
      }
    }
  }
}

// ---------- bf16 MFMA GEMM 64x64 tile (N == 512 shapes), 16KB LDS, XCD-banded ----------
template <int EPI>
__global__ __launch_bounds__(256, 8)
void gemm64b_kernel(const ushort_t* __restrict__ A, const ushort_t* __restrict__ Bt,
                    const float* __restrict__ bias, const float* res,
                    float* outF, ushort_t* outB, unsigned char* out8, int M, int N, int K) {
  __shared__ __align__(16) ushort_t sA[64 * 64];
  __shared__ __align__(16) ushort_t sB[64 * 64];
  const int tid  = threadIdx.x;
  const int lane = tid & 63;
  const int w    = tid >> 6;
  const int wr   = w >> 1, wc = w & 1;     // 2x2 waves, each owns 32x32
  int brc, bcc;
  xcd_rc(blockIdx.x, M >> 6, N >> 6, brc, bcc);
  const long brow = (long)brc * 64;
  const long bcol = (long)bcc * 64;
  const int r16 = lane & 15;
  const int cq  = lane >> 4;
  f32x4 acc[2][2] = {};

  for (int k0 = 0; k0 < K; k0 += 64) {
    __syncthreads();
#pragma unroll
    for (int i = 0; i < 2; ++i) {
      const int c   = i * 256 + tid;
      const int wb  = i * 256 + (tid & ~63);
      const int row = c >> 3;
      const int col = ((c & 7) ^ (row & 7)) << 3;
      gload_lds16(A  + (brow + row) * (long)K + k0 + col, &sA[(long)wb * 8]);
      gload_lds16(Bt + (bcol + row) * (long)K + k0 + col, &sB[(long)wb * 8]);
    }
    __syncthreads();
#pragma unroll
    for (int kkc = 0; kkc < 8; kkc += 4) {
      u32x4 af[2], bfr[2];
#pragma unroll
      for (int i = 0; i < 2; ++i) {
        const int row = wr * 32 + i * 16 + r16;
        af[i] = *(const u32x4*)&sA[row * 64 + (((kkc + cq) ^ (row & 7)) << 3)];
      }
#pragma unroll
      for (int j = 0; j < 2; ++j) {
        const int row = wc * 32 + j * 16 + r16;
        bfr[j] = *(const u32x4*)&sB[row * 64 + (((kkc + cq) ^ (row & 7)) << 3)];
      }
#pragma unroll
      for (int i = 0; i < 2; ++i)
#pragma unroll
        for (int j = 0; j < 2; ++j)
          asm("v_mfma_f32_16x16x32_bf16 %0, %1, %2, %0"
              : "+v"(acc[i][j]) : "v"(af[i]), "v"(bfr[j]));
    }
  }
  asm volatile("s_nop 7\n\ts_nop 7\n\ts_nop 7" ::);

  const long orow = brow + wr * 32;
  const long ocol = bcol + wc * 32;
#pragma unroll
  for (int j = 0; j < 2; ++j) {
    const long c  = ocol + j * 16 + r16;
    const float bv = bias[c];
#pragma unroll
    for (int i = 0; i < 2; ++i) {
      const long r0 = orow + i * 16 + ((lane >> 4) << 2);
#pragma unroll
      for (int r = 0; r < 4; ++r) {
        float v = acc[i][j][r] + bv;
        const long row = r0 + r;
        if (EPI == 0)      outB[row * (long)N + c] = f2bf(v);
        else if (EPI == 1) outB[row * (long)N + c] = f2bf(fmaxf(v, 0.f));
        else if (EPI == 2) outF[row * (long)N + c] = v + res[row * (long)N + c];
        else               store_kv(out8, row, (int)c, v);   // EPI 3: kvi
      }
    }
  }
}

// ---------- CSR build: single-pass counting sort by dst ----------
__global__ void zero_kernel(int* p, int n) {
  int i = blockIdx.x * blockDim.x + threadIdx.x;
  if (i < n) p[i] = 0;
}
__global__ void hist2_kernel(const int* __restrict__ d0, const int* __restrict__ d1,
                             int* __restrict__ counts2, int E) {
  const int* d = blockIdx.y ? d1 : d0;
  int* c = counts2 + blockIdx.y * 8192;
  for (int e = blockIdx.x * blockDim.x + threadIdx.x; e < E; e += gridDim.x * blockDim.x)
    atomicAdd(&c[d[e]], 1);
}
template <int PER, int BINS>
__global__ void scan_kernel(const int* __restrict__ countsN, int* __restrict__ rowstartN,
                            int* __restrict__ cursorN) {
  const int* counts = countsN + blockIdx.x * BINS;
  int* rowstart = rowstartN + blockIdx.x * (BINS + 1);
  int* cursor   = cursorN + blockIdx.x * BINS;
  __shared__ int part[256];
  const int t = threadIdx.x;
  int loc[PER];
  int s = 0;
  const int base = t * PER;
#pragma unroll
  for (int i = 0; i < PER; ++i) { loc[i] = counts[base + i]; s += loc[i]; }
  part[t] = s;
  __syncthreads();
  for (int off = 1; off < 256; off <<= 1) {
    int v2 = (t >= off) ? part[t - off] : 0;
    __syncthreads();
    part[t] += v2;
    __syncthreads();
  }
  int run = part[t] - s;   // exclusive prefix
#pragma unroll
  for (int i = 0; i < PER; ++i) { rowstart[base + i] = run; cursor[base + i] = run; run += loc[i]; }
  if (t == 255) rowstart[BINS] = run;
}
// dst-range-partitioned scatter: block handles only dsts in its range (blockIdx.x & 7).
// Each range's output window (~128KB contiguous) + cursor slice stay in ONE XCD's L2.
__global__ void scatterD_kernel(const int* __restrict__ s0, const int* __restrict__ d0,
                                const int* __restrict__ s1, const int* __restrict__ d1,
                                int* __restrict__ cursorD2,
                                int* __restrict__ o0, int* __restrict__ o1, int E) {
  const int* s = blockIdx.y ? s1 : s0;
  const int* d = blockIdx.y ? d1 : d0;
  int* cur = cursorD2 + blockIdx.y * 8192;
  int* o = blockIdx.y ? o1 : o0;
  const int range  = blockIdx.x & 7;            // dst in [range*1024, range*1024+1024)
  const int group  = blockIdx.x >> 3;
  const int stride = (gridDim.x >> 3) * blockDim.x;
  for (int e = group * blockDim.x + threadIdx.x; e < E; e += stride) {
    const int dv = d[e];
    if ((dv >> 10) == range) {
      const int p = atomicAdd(&cur[dv], 1);
      o[p] = s[e];
    }
  }
}

// ---------- graph attention: one wave per dst, interleaved fp8 kv (1 dwordx4/edge/lane) ----
#define ATT_LOADI(SD, EB)                                                   \
  _Pragma("unroll") for (int jj = 0; jj < 4; ++jj) {                        \
    int e_ = (EB) + jj;                                                     \
    SD[jj] = srcs[e_ < e1 ? e_ : e1 - 1];                                   \
  }
#define ATT_LOADG(KV, SD)                                                   \
  _Pragma("unroll") for (int jj = 0; jj < 4; ++jj)                          \
    KV[jj] = *(const u32x4*)(kvb + (long)SD[jj] * 1024 + boff);
#define ATT_EDGE(KV, VALID)                                                 \
  {                                                                         \
    f32x2 d2_ = {0.f, 0.f};                                                 \
    d2_ += (f32x2)__builtin_amdgcn_cvt_pk_f32_fp8((KV)[0], false) * q2[0];  \
    d2_ += (f32x2)__builtin_amdgcn_cvt_pk_f32_fp8((KV)[0], true)  * q2[1];  \
    d2_ += (f32x2)__builtin_amdgcn_cvt_pk_f32_fp8((KV)[1], false) * q2[2];  \
    d2_ += (f32x2)__builtin_amdgcn_cvt_pk_f32_fp8((KV)[1], true)  * q2[3];  \
    float dot_ = d2_[0] + d2_[1];                                           \
    dot_ += __shfl_xor(dot_, 1);                                            \
    dot_ += __shfl_xor(dot_, 2);                                            \
    dot_ += __shfl_xor(dot_, 4);                                            \
    float sc_ = __expf(fminf(fmaxf(dot_ * 0.125f, -10.f), 10.f));           \
    sc_ = (VALID) ? sc_ : 0.f;                                              \
    z += sc_;                                                               \
    const f32x2 s2_ = {sc_, sc_};                                           \
    av[0] += s2_ * (f32x2)__builtin_amdgcn_cvt_pk_f32_fp8((KV)[2], false);  \
    av[1] += s2_ * (f32x2)__builtin_amdgcn_cvt_pk_f32_fp8((KV)[2], true);   \
    av[2] += s2_ * (f32x2)__builtin_amdgcn_cvt_pk_f32_fp8((KV)[3], false);  \
    av[3] += s2_ * (f32x2)__builtin_amdgcn_cvt_pk_f32_fp8((KV)[3], true);   \
  }
#define ATT_GROUP(GB, KV4)                                                  \
  _Pragma("unroll") for (int jj = 0; jj < 4; ++jj) {                        \
    ATT_EDGE(KV4[jj], ((GB) + jj < n))                                      \
  }

__global__ __launch_bounds__(256)
void attend_kernel(const int* __restrict__ rowstart, const int* __restrict__ srcs,
                   const ushort_t* __restrict__ qb,
                   const unsigned char* __restrict__ kvb,   // kvi [node][1024B]
                   ushort_t* __restrict__ ob) {
  const int d    = blockIdx.x * 4 + (threadIdx.x >> 6);
  const int lane = threadIdx.x & 63;           // lane covers dims lane*8..+7; head = lane>>3
  const int boff = lane * 16;                  // one 16B [k8|v8] unit per lane
  const int e0 = rowstart[d], e1 = rowstart[d + 1];
  const int n  = e1 - e0;
  const u32x4 qv = *(const u32x4*)(qb + (long)d * DD + lane * 8);
  f32x2 q2[4];
#pragma unroll
  for (int u = 0; u < 4; ++u) q2[u] = f32x2{bflo(qv[u]), bfhi(qv[u])};
  f32x2 av[4] = {};
  float z = 0.f;
  if (n > 0) {
    int sA4[4], sB4[4];
    u32x4 kvA[4], kvB[4];
    ATT_LOADI(sA4, e0);
    ATT_LOADI(sB4, e0 + 4);
    ATT_LOADG(kvA, sA4);
    const int ng = (n + 3) >> 2;
    const int NG = (ng + 1) & ~1;            // even # of groups; tail masked by sc=0
    for (int g = 0; g < NG; g += 2) {
      ATT_LOADG(kvB, sB4);                   // issue group g+1 gathers
      ATT_LOADI(sA4, e0 + (g + 2) * 4);      // indices for group g+2
      ATT_GROUP(g * 4, kvA)                  // compute group g
      ATT_LOADG(kvA, sA4);                   // issue group g+2 gathers
      ATT_LOADI(sB4, e0 + (g + 3) * 4);      // indices for group g+3
      ATT_GROUP((g + 1) * 4, kvB)            // compute group g+1
    }
  }
  const float inv = 1.f / z;
  u32x4 o;
#pragma unroll
  for (int u = 0; u < 4; ++u)
    o[u] = (unsigned)f2bf(av[u][0] * inv) | ((unsigned)f2bf(av[u][1] * inv) << 16);
  *(u32x4*)(ob + (long)d * DD + lane * 8) = o;
}

// ---------- host orchestration ----------
extern "C" void kernel_launch(void* const* d_in, const int* in_sizes, int n_in,
                              void* d_out, int out_size, void* d_ws, size_t ws_size,
                              hipStream_t stream) {
  const float* x    = (const float*)d_in[0];
  const float* mem  = (const float*)d_in[1];
  const float* ln0g = (const float*)d_in[2];  const float* ln0b = (const float*)d_in[3];
  const float* ln1g = (const float*)d_in[4];  const float* ln1b = (const float*)d_in[5];
  const float* ln2g = (const float*)d_in[6];  const float* ln2b = (const float*)d_in[7];
  const float* Wq = (const float*)d_in[8];   const float* bq = (const float*)d_in[9];
  const float* Wk = (const float*)d_in[10];  const float* bk = (const float*)d_in[11];
  const float* Wv = (const float*)d_in[12];  const float* bv = (const float*)d_in[13];
  const float* Wo = (const float*)d_in[14];  const float* bo = (const float*)d_in[15];
  const float* W1 = (const float*)d_in[16];  const float* b1 = (const float*)d_in[17];
  const float* W2 = (const float*)d_in[18];  const float* b2 = (const float*)d_in[19];
  const int* src_self  = (const int*)d_in[20];
  const int* dst_self  = (const int*)d_in[21];
  const int* src_cross = (const int*)d_in[22];
  const int* dst_cross = (const int*)d_in[23];
  const int E = in_sizes[20];
  float* out = (float*)d_out;

  char* wsp = (char*)d_ws;
  auto alloc = [&](size_t bytes) {
    char* p = wsp;
    wsp += (bytes + 255) & ~(size_t)255;
    return p;
  };
  ushort_t* Wqkv_t = (ushort_t*)alloc((size_t)1536 * 512 * 2);
  ushort_t* Wo_t   = (ushort_t*)alloc((size_t)512 * 512 * 2);
  ushort_t* W1_t   = (ushort_t*)alloc((size_t)DFF * DD * 2);
  ushort_t* W2_t   = (ushort_t*)alloc((size_t)DD * DFF * 2);
  float*    bqkv   = (float*)alloc(1536 * 4);
  ushort_t* h_bf   = (ushort_t*)alloc((size_t)NN * DD * 2);
  ushort_t* mem_bf = (ushort_t*)alloc((size_t)MMM * DD * 2);
  ushort_t* q_bf   = (ushort_t*)alloc((size_t)NN * DD * 2);         // q (self / cross reuse)
  unsigned char* kvi = (unsigned char*)alloc((size_t)NN * 1024);    // fp8 kv interleaved
  ushort_t* attn_bf= (ushort_t*)alloc((size_t)NN * DD * 2);
  ushort_t* ffh_bf = (ushort_t*)alloc((size_t)NN * DFF * 2);
  int* countsD   = (int*)alloc(2 * 8192 * 4);
  int* rowstartD2= (int*)alloc(2 * 8193 * 4);
  int* cursorD2  = (int*)alloc(2 * 8192 * 4);
  int* srcsA     = (int*)alloc((size_t)E * 4);
  int* srcsB     = (int*)alloc((size_t)E * 4);

  const dim3 B256(256);

  // ---- prep: weights, mem cast, both dst-CSRs (input-only deps) ----
  TW4 tw{Wq, Wk, Wv, Wo, Wqkv_t, Wqkv_t + 512 * 512, Wqkv_t + 1024 * 512, Wo_t};
  transw4_kernel<<<dim3(16, 16, 4), dim3(32, 8), 0, stream>>>(tw);
  transw_kernel<<<dim3(64, 16), dim3(32, 8), 0, stream>>>(W1, W1_t, DD, DFF);
  transw_kernel<<<dim3(16, 64), dim3(32, 8), 0, stream>>>(W2, W2_t, DFF, DD);
  biascat_kernel<<<dim3(6), B256, 0, stream>>>(bq, bk, bv, bqkv);
  tobf_kernel<<<dim3(MMM * DD / 4 / 256), B256, 0, stream>>>(mem, mem_bf, MMM * DD / 4);
  zero_kernel<<<dim3(64), B256, 0, stream>>>(countsD, 2 * 8192);
  hist2_kernel<<<dim3(256, 2), B256, 0, stream>>>(dst_self, dst_cross, countsD, E);
  scan_kernel<32, 8192><<<dim3(2), B256, 0, stream>>>(countsD, rowstartD2, cursorD2);
  scatterD_kernel<<<dim3(256, 2), B256, 0, stream>>>(src_self, dst_self, src_cross, dst_cross,
                                                     cursorD2, srcsA, srcsB, E);

  auto gemm = [&](int mode, const ushort_t* Ap, const ushort_t* Btp, const float* biasp,
                  const float* resp, float* oF, ushort_t* oB, unsigned char* o8,
                  int M_, int N_, int K_) {
    if (N_ <= 512) {                          // N=512 -> 64x64 tiles (4 blocks/CU)
      dim3 g((M_ / 64) * (N_ / 64));
      if (mode == 0)
        gemm64b_kernel<0><<<g, B256, 0, stream>>>(Ap, Btp, biasp, resp, oF, oB, o8, M_, N_, K_);
      else if (mode == 1)
        gemm64b_kernel<1><<<g, B256, 0, stream>>>(Ap, Btp, biasp, resp, oF, oB, o8, M_, N_, K_);
      else if (mode == 2)
        gemm64b_kernel<2><<<g, B256, 0, stream>>>(Ap, Btp, biasp, resp, oF, oB, o8, M_, N_, K_);
      else
        gemm64b_kernel<3><<<g, B256, 0, stream>>>(Ap, Btp, biasp, resp, oF, oB, o8, M_, N_, K_);
    } else {                                  // N>=1024 -> 128x128 tiles (half the traffic)
      dim3 g((M_ / 128) * (N_ / 128));
      if (mode == 0)
        gemm_kernel<0><<<g, B256, 0, stream>>>(Ap, Btp, biasp, resp, oF, oB, o8, M_, N_, K_);
      else if (mode == 1)
        gemm_kernel<1><<<g, B256, 0, stream>>>(Ap, Btp, biasp, resp, oF, oB, o8, M_, N_, K_);
      else if (mode == 2)
        gemm_kernel<2><<<g, B256, 0, stream>>>(Ap, Btp, biasp, resp, oF, oB, o8, M_, N_, K_);
      else if (mode == 3)
        gemm_kernel<3><<<g, B256, 0, stream>>>(Ap, Btp, biasp, resp, oF, oB, o8, M_, N_, K_);
      else
        gemm_kernel<4><<<g, B256, 0, stream>>>(Ap, Btp, biasp, resp, oF, oB, o8, M_, N_, K_);
    }
  };

  // ---- sublayer 0: self-attention ----
  ln_kernel<<<dim3(NN / 4), B256, 0, stream>>>(x, ln0g, ln0b, h_bf);
  gemm(4, h_bf, Wqkv_t, bqkv, nullptr, nullptr, q_bf, kvi, NN, 1536, DD);   // q bf16 | kvi fp8
  attend_kernel<<<dim3(NN / 4), B256, 0, stream>>>(rowstartD2, srcsA, q_bf, kvi, attn_bf);
  gemm(2, attn_bf, Wo_t, bo, x, out, nullptr, nullptr, NN, DD, DD);    // out = x + attn@Wo+bo

  // ---- sublayer 1: cross-attention ----
  ln_kernel<<<dim3(NN / 4), B256, 0, stream>>>(out, ln1g, ln1b, h_bf);
  gemm(0, h_bf, Wqkv_t, bqkv, nullptr, nullptr, q_bf, nullptr, NN, 512, DD);         // q bf16
  gemm(3, mem_bf, Wqkv_t + 512 * 512, bqkv + 512, nullptr, nullptr, nullptr, kvi,
       MMM, 1024, DD);                                                 // k|v fp8 kvi (no LN)
  attend_kernel<<<dim3(NN / 4), B256, 0, stream>>>(rowstartD2 + 8193, srcsB, q_bf, kvi, attn_bf);
  gemm(2, attn_bf, Wo_t, bo, out, out, nullptr, nullptr, NN, DD, DD);  // out += attn@Wo+bo

  // ---- sublayer 2: feed-forward ----
  ln_kernel<<<dim3(NN / 4), B256, 0, stream>>>(out, ln2g, ln2b, h_bf);
  gemm(1, h_bf, W1_t, b1, nullptr, nullptr, ffh_bf, nullptr, NN, DFF, DD);   // relu, bf16 out
  gemm(2, ffh_bf, W2_t, b2, out, out, nullptr, nullptr, NN, DD, DFF);        // out += ff@W2+b2

  (void)n_in; (void)out_size; (void)ws_size; (void)in_sizes;
}